// Round 1
// baseline (1870.994 us; speedup 1.0000x reference)
//
#include <hip/hip_runtime.h>
#include <math.h>

#define B_  2
#define L_  2048
#define D_  256
#define H_  8
#define HD_ 32
#define F_  1024
#define LY_ 4
#define M_  (B_*L_)

// ---------------------------------------------------------------------------
// GEMM: C[M,N] = epi(A[M,K] @ W[K,N] + bias[N])
// EPI: 0 = none, 1 = exact GELU, 2 = + residual (res may alias C)
// Tiles: BM=BN=64, BK=16, 256 threads, 4x4 per-thread register tile.
// ---------------------------------------------------------------------------
template<int EPI>
__global__ __launch_bounds__(256) void gemm_epi(
    const float* __restrict__ A, const float* __restrict__ W,
    const float* __restrict__ bias, const float* __restrict__ res,
    float* __restrict__ C, int M, int N, int K)
{
    __shared__ __align__(16) float sA[16][72];  // [k][row], stride 72 (16B-mult, de-conflicted)
    __shared__ __align__(16) float sW[16][64];  // [k][col]

    const int tid = threadIdx.x;
    const int tx  = tid & 15;        // col group 0..15
    const int ty  = tid >> 4;        // row group 0..15
    const int row0 = blockIdx.y * 64;
    const int col0 = blockIdx.x * 64;

    const int arow = tid >> 2;           // 0..63
    const int acol = (tid & 3) * 4;      // 0,4,8,12
    const int wrow = tid >> 4;           // 0..15
    const int wcol = (tid & 15) * 4;     // 0..60

    float c[4][4] = {};

    for (int kt = 0; kt < K; kt += 16) {
        float4 a4 = *reinterpret_cast<const float4*>(&A[(row0 + arow) * K + kt + acol]);
        float4 w4 = *reinterpret_cast<const float4*>(&W[(kt + wrow) * N + col0 + wcol]);
        __syncthreads();   // protect previous iteration's reads
        sA[acol + 0][arow] = a4.x;
        sA[acol + 1][arow] = a4.y;
        sA[acol + 2][arow] = a4.z;
        sA[acol + 3][arow] = a4.w;
        *reinterpret_cast<float4*>(&sW[wrow][wcol]) = w4;
        __syncthreads();
#pragma unroll
        for (int k = 0; k < 16; ++k) {
            float4 av = *reinterpret_cast<const float4*>(&sA[k][ty * 4]);
            float4 wv = *reinterpret_cast<const float4*>(&sW[k][tx * 4]);
            float aa[4] = {av.x, av.y, av.z, av.w};
            float ww[4] = {wv.x, wv.y, wv.z, wv.w};
#pragma unroll
            for (int i = 0; i < 4; ++i)
#pragma unroll
                for (int j = 0; j < 4; ++j)
                    c[i][j] = fmaf(aa[i], ww[j], c[i][j]);
        }
    }

#pragma unroll
    for (int i = 0; i < 4; ++i) {
        const int r = row0 + ty * 4 + i;
#pragma unroll
        for (int j = 0; j < 4; ++j) {
            const int cc = col0 + tx * 4 + j;
            float v = c[i][j] + bias[cc];
            if (EPI == 1) v = 0.5f * v * (1.0f + erff(v * 0.70710678118654752f));
            if (EPI == 2) v += res[r * N + cc];
            C[r * N + cc] = v;
        }
    }
}

// ---------------------------------------------------------------------------
// LayerNorm over D=256: one block (256 threads) per row.
// ---------------------------------------------------------------------------
__global__ __launch_bounds__(256) void ln_kernel(
    const float* __restrict__ x, const float* __restrict__ g,
    const float* __restrict__ b, float* __restrict__ y)
{
    const int row = blockIdx.x;
    const int tid = threadIdx.x;
    const float v = x[row * D_ + tid];
    float s = v, s2 = v * v;
#pragma unroll
    for (int off = 32; off > 0; off >>= 1) {
        s  += __shfl_xor(s,  off);
        s2 += __shfl_xor(s2, off);
    }
    __shared__ float ls[4], ls2[4];
    const int wid = tid >> 6;
    if ((tid & 63) == 0) { ls[wid] = s; ls2[wid] = s2; }
    __syncthreads();
    s  = ls[0]  + ls[1]  + ls[2]  + ls[3];
    s2 = ls2[0] + ls2[1] + ls2[2] + ls2[3];
    const float m   = s * (1.0f / D_);
    const float var = s2 * (1.0f / D_) - m * m;
    const float r   = rsqrtf(var + 1e-5f);
    y[row * D_ + tid] = (v - m) * r * g[tid] + b[tid];
}

// ---------------------------------------------------------------------------
// Evidence attention for one (b,h): block = 64 threads, 32 queries.
// Lanes 0..31 handle keys [0,1024), lanes 32..63 handle keys [1024,2048);
// halves combined with __shfl_xor(.,32). No max-subtraction: scores are small
// (weights 0.02-scaled) and the reference uses raw exp.
//   ev    = exp(q.k/sqrt(32)) * scale + (1 + bias)
//   out   = sum(ev * V) / sum(ev);  unc = L / sum(ev)
// ---------------------------------------------------------------------------
__global__ __launch_bounds__(64) void attn_kernel(
    const float* __restrict__ Q, const float* __restrict__ K,
    const float* __restrict__ V, float* __restrict__ O,
    float* __restrict__ unc, const float* __restrict__ ev_scale,
    const float* __restrict__ ev_bias, int layer)
{
    const int bh  = blockIdx.y;         // b*H + h
    const int b   = bh >> 3;
    const int h   = bh & 7;
    const int tid = threadIdx.x;
    const int hf  = tid >> 5;           // key-range half
    const int qi  = tid & 31;
    const int q   = blockIdx.x * 32 + qi;
    const float scale = ev_scale[layer];
    const float cb    = 1.0f + ev_bias[layer];
    const float isq   = 0.17677669529663687f;  // 1/sqrt(32)

    float qv[32];
    const float* qptr = &Q[(b * L_ + q) * D_ + h * HD_];
#pragma unroll
    for (int i = 0; i < 8; ++i) {
        float4 t = reinterpret_cast<const float4*>(qptr)[i];
        qv[4*i+0] = t.x; qv[4*i+1] = t.y; qv[4*i+2] = t.z; qv[4*i+3] = t.w;
    }

    float acc[32] = {};
    float esum = 0.0f;

    __shared__ __align__(16) float sK[64][32];
    __shared__ __align__(16) float sV[64][32];

    for (int t = 0; t < 32; ++t) {      // 32 tiles x 32 keys per half
        __syncthreads();
#pragma unroll
        for (int j = 0; j < 8; ++j) {
            const int i   = tid + j * 64;
            const int row = i >> 3;
            const int c4  = i & 7;
            const int key = (row >> 5) * 1024 + t * 32 + (row & 31);
            const float4 kk = reinterpret_cast<const float4*>(&K[(b * L_ + key) * D_ + h * HD_])[c4];
            const float4 vv = reinterpret_cast<const float4*>(&V[(b * L_ + key) * D_ + h * HD_])[c4];
            reinterpret_cast<float4*>(&sK[row][0])[c4] = kk;
            reinterpret_cast<float4*>(&sV[row][0])[c4] = vv;
        }
        __syncthreads();
        for (int r = 0; r < 32; ++r) {
            const float* kr = sK[hf * 32 + r];
            float s = 0.0f;
#pragma unroll
            for (int d = 0; d < 32; ++d) s = fmaf(qv[d], kr[d], s);
            const float ev = fmaf(__expf(s * isq), scale, cb);
            esum += ev;
            const float* vr = sV[hf * 32 + r];
#pragma unroll
            for (int d = 0; d < 32; ++d) acc[d] = fmaf(ev, vr[d], acc[d]);
        }
    }

    esum += __shfl_xor(esum, 32);
#pragma unroll
    for (int d = 0; d < 32; ++d) acc[d] += __shfl_xor(acc[d], 32);

    if (hf == 0) {
        const float inv = 1.0f / esum;
        float* optr = &O[(b * L_ + q) * D_ + h * HD_];
#pragma unroll
        for (int i = 0; i < 8; ++i) {
            float4 t4 = make_float4(acc[4*i] * inv, acc[4*i+1] * inv,
                                    acc[4*i+2] * inv, acc[4*i+3] * inv);
            reinterpret_cast<float4*>(optr)[i] = t4;
        }
        const float u = (float)L_ * inv;
        const int uidx = bh * L_ + q;
        unc[uidx] = (layer == 0) ? u : (unc[uidx] + u);   // '=' on layer 0: deterministic
    }
}

// ---------------------------------------------------------------------------
// avg_unc = unc/4 ; abstain = avg_unc > 0.3
// ---------------------------------------------------------------------------
__global__ __launch_bounds__(256) void unc_final(
    const float* __restrict__ unc, float* __restrict__ out_unc,
    float* __restrict__ out_abst)
{
    const int i = blockIdx.x * 256 + threadIdx.x;
    const float u = unc[i] * 0.25f;
    out_unc[i]  = u;
    out_abst[i] = (u > 0.3f) ? 1.0f : 0.0f;
}

// ---------------------------------------------------------------------------
extern "C" void kernel_launch(void* const* d_in, const int* in_sizes, int n_in,
                              void* d_out, int out_size, void* d_ws, size_t ws_size,
                              hipStream_t stream)
{
    const float* x    = (const float*)d_in[0];
    const float* Win  = (const float*)d_in[1];
    const float* bin_ = (const float*)d_in[2];
    const float* Wq   = (const float*)d_in[3];
    const float* bq   = (const float*)d_in[4];
    const float* Wk   = (const float*)d_in[5];
    const float* bk   = (const float*)d_in[6];
    const float* Wv   = (const float*)d_in[7];
    const float* bv   = (const float*)d_in[8];
    const float* Wo   = (const float*)d_in[9];
    const float* bo   = (const float*)d_in[10];
    const float* evs  = (const float*)d_in[11];
    const float* evb  = (const float*)d_in[12];
    const float* W1   = (const float*)d_in[13];
    const float* b1   = (const float*)d_in[14];
    const float* W2   = (const float*)d_in[15];
    const float* b2   = (const float*)d_in[16];
    const float* n1g  = (const float*)d_in[17];
    const float* n1b  = (const float*)d_in[18];
    const float* n2g  = (const float*)d_in[19];
    const float* n2b  = (const float*)d_in[20];
    const float* fng  = (const float*)d_in[21];
    const float* fnb  = (const float*)d_in[22];
    const float* Wout = (const float*)d_in[23];
    const float* bout = (const float*)d_in[24];

    char* ws = (char*)d_ws;
    float* h    = (float*)(ws);                 // 4 MB
    float* tmp  = (float*)(ws + (4  << 20));    // 4 MB (LN out)
    float* Qb   = (float*)(ws + (8  << 20));    // 4 MB
    float* Kb   = (float*)(ws + (12 << 20));    // 4 MB
    float* Vb   = (float*)(ws + (16 << 20));    // 4 MB
    float* attn = (float*)(ws + (20 << 20));    // 4 MB
    float* ff   = (float*)(ws + (8  << 20));    // 16 MB, overlays Q/K/V/attn (dead by FF1)
    float* unc  = (float*)(ws + (24 << 20));    // 128 KB

    float* out_main = (float*)d_out;
    float* out_unc  = out_main + M_ * D_;
    float* out_abst = out_unc + B_ * H_ * L_;

    const dim3 blk(256);
    const dim3 g256(D_ / 64, M_ / 64);   // N=256
    const dim3 g1024(F_ / 64, M_ / 64);  // N=1024
    const dim3 gattn(L_ / 32, B_ * H_);

    // h = x @ Win + bin
    gemm_epi<0><<<g256, blk, 0, stream>>>(x, Win, bin_, nullptr, h, M_, D_, D_);

    for (int i = 0; i < LY_; ++i) {
        ln_kernel<<<M_, 256, 0, stream>>>(h, n1g + i * D_, n1b + i * D_, tmp);
        gemm_epi<0><<<g256, blk, 0, stream>>>(tmp, Wq + i * D_ * D_, bq + i * D_, nullptr, Qb, M_, D_, D_);
        gemm_epi<0><<<g256, blk, 0, stream>>>(tmp, Wk + i * D_ * D_, bk + i * D_, nullptr, Kb, M_, D_, D_);
        gemm_epi<0><<<g256, blk, 0, stream>>>(tmp, Wv + i * D_ * D_, bv + i * D_, nullptr, Vb, M_, D_, D_);
        attn_kernel<<<gattn, 64, 0, stream>>>(Qb, Kb, Vb, attn, unc, evs, evb, i);
        // h += attn @ Wo + bo   (in-place residual)
        gemm_epi<2><<<g256, blk, 0, stream>>>(attn, Wo + i * D_ * D_, bo + i * D_, h, h, M_, D_, D_);
        ln_kernel<<<M_, 256, 0, stream>>>(h, n2g + i * D_, n2b + i * D_, tmp);
        gemm_epi<1><<<g1024, blk, 0, stream>>>(tmp, W1 + i * D_ * F_, b1 + i * F_, nullptr, ff, M_, F_, D_);
        // h += ff @ W2 + b2
        gemm_epi<2><<<g256, blk, 0, stream>>>(ff, W2 + i * F_ * D_, b2 + i * D_, h, h, M_, D_, F_);
    }

    ln_kernel<<<M_, 256, 0, stream>>>(h, fng, fnb, tmp);
    gemm_epi<0><<<g256, blk, 0, stream>>>(tmp, Wout, bout, nullptr, out_main, M_, D_, D_);
    unc_final<<<(B_ * H_ * L_) / 256, 256, 0, stream>>>(unc, out_unc, out_abst);
}

// Round 2
// 1018.434 us; speedup vs baseline: 1.8371x; 1.8371x over previous
//
#include <hip/hip_runtime.h>
#include <hip/hip_bf16.h>
#include <math.h>

#define B_  2
#define L_  2048
#define D_  256
#define H_  8
#define HD_ 32
#define F_  1024
#define LY_ 4
#define M_  (B_*L_)

typedef __attribute__((ext_vector_type(8))) short bf16x8;   // 8 bf16 in 4 VGPRs
typedef __attribute__((ext_vector_type(4))) float f32x4;

static __device__ __forceinline__ short f2bf(float f) {
    return __builtin_bit_cast(short, __float2bfloat16(f));
}

// ---------------------------------------------------------------------------
// GEMM: C[M,N] = epi(A[M,K] @ W[K,N] + bias[N])   (unchanged from round 1)
// ---------------------------------------------------------------------------
template<int EPI>
__global__ __launch_bounds__(256) void gemm_epi(
    const float* __restrict__ A, const float* __restrict__ W,
    const float* __restrict__ bias, const float* __restrict__ res,
    float* __restrict__ C, int M, int N, int K)
{
    __shared__ __align__(16) float sA[16][72];
    __shared__ __align__(16) float sW[16][64];

    const int tid = threadIdx.x;
    const int tx  = tid & 15;
    const int ty  = tid >> 4;
    const int row0 = blockIdx.y * 64;
    const int col0 = blockIdx.x * 64;

    const int arow = tid >> 2;
    const int acol = (tid & 3) * 4;
    const int wrow = tid >> 4;
    const int wcol = (tid & 15) * 4;

    float c[4][4] = {};

    for (int kt = 0; kt < K; kt += 16) {
        float4 a4 = *reinterpret_cast<const float4*>(&A[(row0 + arow) * K + kt + acol]);
        float4 w4 = *reinterpret_cast<const float4*>(&W[(kt + wrow) * N + col0 + wcol]);
        __syncthreads();
        sA[acol + 0][arow] = a4.x;
        sA[acol + 1][arow] = a4.y;
        sA[acol + 2][arow] = a4.z;
        sA[acol + 3][arow] = a4.w;
        *reinterpret_cast<float4*>(&sW[wrow][wcol]) = w4;
        __syncthreads();
#pragma unroll
        for (int k = 0; k < 16; ++k) {
            float4 av = *reinterpret_cast<const float4*>(&sA[k][ty * 4]);
            float4 wv = *reinterpret_cast<const float4*>(&sW[k][tx * 4]);
            float aa[4] = {av.x, av.y, av.z, av.w};
            float ww[4] = {wv.x, wv.y, wv.z, wv.w};
#pragma unroll
            for (int i = 0; i < 4; ++i)
#pragma unroll
                for (int j = 0; j < 4; ++j)
                    c[i][j] = fmaf(aa[i], ww[j], c[i][j]);
        }
    }

#pragma unroll
    for (int i = 0; i < 4; ++i) {
        const int r = row0 + ty * 4 + i;
#pragma unroll
        for (int j = 0; j < 4; ++j) {
            const int cc = col0 + tx * 4 + j;
            float v = c[i][j] + bias[cc];
            if (EPI == 1) v = 0.5f * v * (1.0f + erff(v * 0.70710678118654752f));
            if (EPI == 2) v += res[r * N + cc];
            C[r * N + cc] = v;
        }
    }
}

// ---------------------------------------------------------------------------
// LayerNorm over D=256: one block (256 threads) per row.  (unchanged)
// ---------------------------------------------------------------------------
__global__ __launch_bounds__(256) void ln_kernel(
    const float* __restrict__ x, const float* __restrict__ g,
    const float* __restrict__ b, float* __restrict__ y)
{
    const int row = blockIdx.x;
    const int tid = threadIdx.x;
    const float v = x[row * D_ + tid];
    float s = v, s2 = v * v;
#pragma unroll
    for (int off = 32; off > 0; off >>= 1) {
        s  += __shfl_xor(s,  off);
        s2 += __shfl_xor(s2, off);
    }
    __shared__ float ls[4], ls2[4];
    const int wid = tid >> 6;
    if ((tid & 63) == 0) { ls[wid] = s; ls2[wid] = s2; }
    __syncthreads();
    s  = ls[0]  + ls[1]  + ls[2]  + ls[3];
    s2 = ls2[0] + ls2[1] + ls2[2] + ls2[3];
    const float m   = s * (1.0f / D_);
    const float var = s2 * (1.0f / D_) - m * m;
    const float r   = rsqrtf(var + 1e-5f);
    y[row * D_ + tid] = (v - m) * r * g[tid] + b[tid];
}

// ---------------------------------------------------------------------------
// MFMA evidence attention. One wave per (bh, 16-query tile). Zero LDS.
//
// Swapped QK^T: S^T[key][q] = mfma_16x16x32(A=K-frag, B=Q-frag).
//   A-frag: lane(g=l>>4, n=l&15) slot j -> K[row = t + n][d = g*8+j]
//   B-frag:                      slot j -> Q[q0 + n]  [d = g*8+j]
//   C-out : s[r] = score(q = q0+n, key = t + g*4 + r)      (verified C layout)
// Evidence: ev = exp(s/sqrt(32))*scale + (1+bias); esum accumulates plainly
// (no online max — reference uses raw exp).
// PV: O^T = mfma(A=V-frag, B=P-frag). P packed from the two S tiles:
//   pa[j] : j<4 -> key t+g*4+j ; j>=4 -> key t+16+g*4+(j-4)
//   V-frag loads use the SAME slot->key map, so any HW k-slot permutation
//   cancels (identical for A and B operands).
//   acc0: O[q][d=g*4+r], acc1: O[q][d=16+g*4+r]
// ---------------------------------------------------------------------------
__global__ __launch_bounds__(64) void attn_mfma(
    const float* __restrict__ Q, const float* __restrict__ K,
    const float* __restrict__ V, float* __restrict__ O,
    float* __restrict__ unc, const float* __restrict__ ev_scale,
    const float* __restrict__ ev_bias, int layer)
{
    const int bh = blockIdx.y;
    const int b  = bh >> 3;
    const int h  = bh & 7;
    const int q0 = blockIdx.x * 16;
    const int lane = threadIdx.x;
    const int g = lane >> 4;          // lane group 0..3
    const int n = lane & 15;          // q-col / key-row / d-col selector
    const float scale = ev_scale[layer];
    const float cb    = 1.0f + ev_bias[layer];
    const float isq   = 0.17677669529663687f;   // 1/sqrt(32)

    const size_t plane = (size_t)b * L_ * D_ + (size_t)h * HD_;

    // Q fragment (held all kernel)
    bf16x8 qf;
    {
        const float* qp = Q + plane + (size_t)(q0 + n) * D_ + g * 8;
        float4 a = *reinterpret_cast<const float4*>(qp);
        float4 c = *reinterpret_cast<const float4*>(qp + 4);
        qf[0]=f2bf(a.x); qf[1]=f2bf(a.y); qf[2]=f2bf(a.z); qf[3]=f2bf(a.w);
        qf[4]=f2bf(c.x); qf[5]=f2bf(c.y); qf[6]=f2bf(c.z); qf[7]=f2bf(c.w);
    }

    const float* kb = K + plane + g * 8;   // + row*D_
    const float* vb = V + plane + n;       // + row*D_ (+16 for d-high half)

    f32x4 acc0 = {0.f, 0.f, 0.f, 0.f};
    f32x4 acc1 = {0.f, 0.f, 0.f, 0.f};
    const f32x4 zero = {0.f, 0.f, 0.f, 0.f};
    float esum = 0.f;

    for (int t = 0; t < L_; t += 32) {
        // --- K fragments: rows t+n and t+16+n, cols g*8..g*8+7
        const float* k0 = kb + (size_t)(t + n) * D_;
        const float* k1 = k0 + 16 * D_;
        bf16x8 kf0, kf1;
        {
            float4 a = *reinterpret_cast<const float4*>(k0);
            float4 c = *reinterpret_cast<const float4*>(k0 + 4);
            kf0[0]=f2bf(a.x); kf0[1]=f2bf(a.y); kf0[2]=f2bf(a.z); kf0[3]=f2bf(a.w);
            kf0[4]=f2bf(c.x); kf0[5]=f2bf(c.y); kf0[6]=f2bf(c.z); kf0[7]=f2bf(c.w);
        }
        {
            float4 a = *reinterpret_cast<const float4*>(k1);
            float4 c = *reinterpret_cast<const float4*>(k1 + 4);
            kf1[0]=f2bf(a.x); kf1[1]=f2bf(a.y); kf1[2]=f2bf(a.z); kf1[3]=f2bf(a.w);
            kf1[4]=f2bf(c.x); kf1[5]=f2bf(c.y); kf1[6]=f2bf(c.z); kf1[7]=f2bf(c.w);
        }

        f32x4 s0 = __builtin_amdgcn_mfma_f32_16x16x32_bf16(kf0, qf, zero, 0, 0, 0);
        f32x4 s1 = __builtin_amdgcn_mfma_f32_16x16x32_bf16(kf1, qf, zero, 0, 0, 0);

        // --- V fragments: slot j -> row t + (j>>2)*16 + g*4 + (j&3), col n / n+16
        const float* vlo = vb + (size_t)(t + g * 4) * D_;
        const float* vhi = vlo + 16 * D_;
        bf16x8 vf0, vf1;
#pragma unroll
        for (int j = 0; j < 4; ++j) {
            vf0[j]     = f2bf(vlo[j * D_]);
            vf0[j + 4] = f2bf(vhi[j * D_]);
            vf1[j]     = f2bf(vlo[j * D_ + 16]);
            vf1[j + 4] = f2bf(vhi[j * D_ + 16]);
        }

        // --- evidence elementwise + P pack (same slot->key map as V)
        bf16x8 pa;
#pragma unroll
        for (int r = 0; r < 4; ++r) {
            float e = fmaf(__expf(s0[r] * isq), scale, cb);
            esum += e;
            pa[r] = f2bf(e);
        }
#pragma unroll
        for (int r = 0; r < 4; ++r) {
            float e = fmaf(__expf(s1[r] * isq), scale, cb);
            esum += e;
            pa[r + 4] = f2bf(e);
        }

        acc0 = __builtin_amdgcn_mfma_f32_16x16x32_bf16(vf0, pa, acc0, 0, 0, 0);
        acc1 = __builtin_amdgcn_mfma_f32_16x16x32_bf16(vf1, pa, acc1, 0, 0, 0);
    }

    // esum(q): reduce across the 4 lane groups (lanes sharing l&15)
    esum += __shfl_xor(esum, 16);
    esum += __shfl_xor(esum, 32);
    const float inv = 1.0f / esum;

    float* op = O + plane + (size_t)(q0 + n) * D_ + g * 4;
    float4 o0 = make_float4(acc0[0]*inv, acc0[1]*inv, acc0[2]*inv, acc0[3]*inv);
    float4 o1 = make_float4(acc1[0]*inv, acc1[1]*inv, acc1[2]*inv, acc1[3]*inv);
    *reinterpret_cast<float4*>(op)      = o0;
    *reinterpret_cast<float4*>(op + 16) = o1;

    if (g == 0) {
        const float u = (float)L_ * inv;
        const int uidx = bh * L_ + q0 + n;
        unc[uidx] = (layer == 0) ? u : (unc[uidx] + u);   // '=' on layer 0: deterministic
    }
}

// ---------------------------------------------------------------------------
// avg_unc = unc/4 ; abstain = avg_unc > 0.3
// ---------------------------------------------------------------------------
__global__ __launch_bounds__(256) void unc_final(
    const float* __restrict__ unc, float* __restrict__ out_unc,
    float* __restrict__ out_abst)
{
    const int i = blockIdx.x * 256 + threadIdx.x;
    const float u = unc[i] * 0.25f;
    out_unc[i]  = u;
    out_abst[i] = (u > 0.3f) ? 1.0f : 0.0f;
}

// ---------------------------------------------------------------------------
extern "C" void kernel_launch(void* const* d_in, const int* in_sizes, int n_in,
                              void* d_out, int out_size, void* d_ws, size_t ws_size,
                              hipStream_t stream)
{
    const float* x    = (const float*)d_in[0];
    const float* Win  = (const float*)d_in[1];
    const float* bin_ = (const float*)d_in[2];
    const float* Wq   = (const float*)d_in[3];
    const float* bq   = (const float*)d_in[4];
    const float* Wk   = (const float*)d_in[5];
    const float* bk   = (const float*)d_in[6];
    const float* Wv   = (const float*)d_in[7];
    const float* bv   = (const float*)d_in[8];
    const float* Wo   = (const float*)d_in[9];
    const float* bo   = (const float*)d_in[10];
    const float* evs  = (const float*)d_in[11];
    const float* evb  = (const float*)d_in[12];
    const float* W1   = (const float*)d_in[13];
    const float* b1   = (const float*)d_in[14];
    const float* W2   = (const float*)d_in[15];
    const float* b2   = (const float*)d_in[16];
    const float* n1g  = (const float*)d_in[17];
    const float* n1b  = (const float*)d_in[18];
    const float* n2g  = (const float*)d_in[19];
    const float* n2b  = (const float*)d_in[20];
    const float* fng  = (const float*)d_in[21];
    const float* fnb  = (const float*)d_in[22];
    const float* Wout = (const float*)d_in[23];
    const float* bout = (const float*)d_in[24];

    char* ws = (char*)d_ws;
    float* h    = (float*)(ws);                 // 4 MB
    float* tmp  = (float*)(ws + (4  << 20));    // 4 MB (LN out)
    float* Qb   = (float*)(ws + (8  << 20));    // 4 MB
    float* Kb   = (float*)(ws + (12 << 20));    // 4 MB
    float* Vb   = (float*)(ws + (16 << 20));    // 4 MB
    float* attn = (float*)(ws + (20 << 20));    // 4 MB
    float* ff   = (float*)(ws + (8  << 20));    // 16 MB, overlays Q/K/V/attn (dead by FF1)
    float* unc  = (float*)(ws + (24 << 20));    // 128 KB

    float* out_main = (float*)d_out;
    float* out_unc  = out_main + M_ * D_;
    float* out_abst = out_unc + B_ * H_ * L_;

    const dim3 blk(256);
    const dim3 g256(D_ / 64, M_ / 64);   // N=256
    const dim3 g1024(F_ / 64, M_ / 64);  // N=1024
    const dim3 gattn(L_ / 16, B_ * H_);

    // h = x @ Win + bin
    gemm_epi<0><<<g256, blk, 0, stream>>>(x, Win, bin_, nullptr, h, M_, D_, D_);

    for (int i = 0; i < LY_; ++i) {
        ln_kernel<<<M_, 256, 0, stream>>>(h, n1g + i * D_, n1b + i * D_, tmp);
        gemm_epi<0><<<g256, blk, 0, stream>>>(tmp, Wq + i * D_ * D_, bq + i * D_, nullptr, Qb, M_, D_, D_);
        gemm_epi<0><<<g256, blk, 0, stream>>>(tmp, Wk + i * D_ * D_, bk + i * D_, nullptr, Kb, M_, D_, D_);
        gemm_epi<0><<<g256, blk, 0, stream>>>(tmp, Wv + i * D_ * D_, bv + i * D_, nullptr, Vb, M_, D_, D_);
        attn_mfma<<<gattn, 64, 0, stream>>>(Qb, Kb, Vb, attn, unc, evs, evb, i);
        // h += attn @ Wo + bo   (in-place residual)
        gemm_epi<2><<<g256, blk, 0, stream>>>(attn, Wo + i * D_ * D_, bo + i * D_, h, h, M_, D_, D_);
        ln_kernel<<<M_, 256, 0, stream>>>(h, n2g + i * D_, n2b + i * D_, tmp);
        gemm_epi<1><<<g1024, blk, 0, stream>>>(tmp, W1 + i * D_ * F_, b1 + i * F_, nullptr, ff, M_, F_, D_);
        // h += ff @ W2 + b2
        gemm_epi<2><<<g256, blk, 0, stream>>>(ff, W2 + i * F_ * D_, b2 + i * D_, h, h, M_, D_, F_);
    }

    ln_kernel<<<M_, 256, 0, stream>>>(h, fng, fnb, tmp);
    gemm_epi<0><<<g256, blk, 0, stream>>>(tmp, Wout, bout, nullptr, out_main, M_, D_, D_);
    unc_final<<<(B_ * H_ * L_) / 256, 256, 0, stream>>>(unc, out_unc, out_abst);
}

// Round 3
// 580.718 us; speedup vs baseline: 3.2219x; 1.7538x over previous
//
#include <hip/hip_runtime.h>
#include <hip/hip_bf16.h>
#include <math.h>

#define B_  2
#define L_  2048
#define D_  256
#define H_  8
#define HD_ 32
#define F_  1024
#define LY_ 4
#define M_  (B_*L_)

typedef __attribute__((ext_vector_type(8))) short bf16x8;   // 8 bf16 in 4 VGPRs
typedef __attribute__((ext_vector_type(4))) float f32x4;

static __device__ __forceinline__ short f2bf(float f) {
    return __builtin_bit_cast(short, __float2bfloat16(f));
}

// ---------------------------------------------------------------------------
// Weight transpose + fp32->bf16:  W[K][N] -> Wt[N][K] bf16, all matrices in
// one dispatch. 32x32 tiles, LDS-staged. Block->matrix map is hardcoded.
// Tile counts: Win 64 | Wq/Wk/Wv/Wo 4x4x64=1024 | W1 1024 | W2 1024 | Wout 64
// ---------------------------------------------------------------------------
__global__ __launch_bounds__(256) void transpose_weights(
    const float* __restrict__ Win, const float* __restrict__ Wq,
    const float* __restrict__ Wk,  const float* __restrict__ Wv,
    const float* __restrict__ Wo,  const float* __restrict__ W1,
    const float* __restrict__ W2,  const float* __restrict__ Wout,
    ushort* __restrict__ T)
{
    const int bid = blockIdx.x;
    const float* src; ushort* dst; int K, N, tt;
    if (bid < 64)        { src = Win; dst = T; K = 256; N = 256; tt = bid; }
    else if (bid < 1088) {
        int i = bid - 64; int which = i >> 8; int l = (i >> 6) & 3; tt = i & 63;
        K = 256; N = 256;
        const float* s4[4] = {Wq, Wk, Wv, Wo};
        src = s4[which] + l * 65536;
        dst = T + 65536 * (1 + which * 4 + l);
    } else if (bid < 2112) {
        int i = bid - 1088; int l = i >> 8; tt = i & 255; K = 256; N = 1024;
        src = W1 + l * 262144; dst = T + 65536 * 17 + l * 262144;
    } else if (bid < 3136) {
        int i = bid - 2112; int l = i >> 8; tt = i & 255; K = 1024; N = 256;
        src = W2 + l * 262144; dst = T + 65536 * 17 + 1048576 + l * 262144;
    } else {
        src = Wout; dst = T + 65536 * 17 + 2097152; K = 256; N = 256; tt = bid - 3136;
    }
    const int ntn = N >> 5;
    const int tk = tt / ntn, tn = tt % ntn;
    __shared__ float ld[32][33];
    const int t = threadIdx.x;
    const int r = t >> 3, c4 = (t & 7) * 4;
    float4 v = *reinterpret_cast<const float4*>(&src[(size_t)(tk * 32 + r) * N + tn * 32 + c4]);
    ld[r][c4 + 0] = v.x; ld[r][c4 + 1] = v.y; ld[r][c4 + 2] = v.z; ld[r][c4 + 3] = v.w;
    __syncthreads();
    short4 o;
    o.x = f2bf(ld[c4 + 0][r]);
    o.y = f2bf(ld[c4 + 1][r]);
    o.z = f2bf(ld[c4 + 2][r]);
    o.w = f2bf(ld[c4 + 3][r]);
    *reinterpret_cast<short4*>(&dst[(size_t)(tn * 32 + r) * K + tk * 32 + c4]) = o;
}

// ---------------------------------------------------------------------------
// fp32 -> bf16 elementwise (x input)
// ---------------------------------------------------------------------------
__global__ __launch_bounds__(256) void f32_to_bf16(
    const float* __restrict__ in, ushort* __restrict__ out)
{
    const int i = (blockIdx.x * 256 + threadIdx.x) * 4;
    float4 v = *reinterpret_cast<const float4*>(&in[i]);
    short4 o = {f2bf(v.x), f2bf(v.y), f2bf(v.z), f2bf(v.w)};
    *reinterpret_cast<short4*>(&out[i]) = o;
}

// ---------------------------------------------------------------------------
// bf16 MFMA GEMM core: C64x64 = A[M][K] @ Wt[N][K]^T, 4 waves (2x2), each
// wave a 32x32 sub-tile via 2x2 16x16x32 frags. LDS rows padded to 56 ushorts
// (112B, 16B-aligned, 2-way banks = free).
// ---------------------------------------------------------------------------
__device__ __forceinline__ void gemm_core64(
    const ushort* __restrict__ A, const ushort* __restrict__ Wt, int K,
    int row0, int col0, ushort* sA, ushort* sW, f32x4 acc[2][2])
{
    const int tid  = threadIdx.x;
    const int lane = tid & 63;
    const int wid  = tid >> 6;
    const int wr = wid >> 1, wc = wid & 1;
    const int g = lane >> 4, nn = lane & 15;
    const int srow = tid >> 2, sch = (tid & 3) * 8;

    const ushort* Ap = &A[(size_t)(row0 + srow) * K + sch];
    const ushort* Wp = &Wt[(size_t)(col0 + srow) * K + sch];

    for (int k0 = 0; k0 < K; k0 += 32) {
        bf16x8 av = *reinterpret_cast<const bf16x8*>(Ap + k0);
        bf16x8 wv = *reinterpret_cast<const bf16x8*>(Wp + k0);
        __syncthreads();
        *reinterpret_cast<bf16x8*>(&sA[srow * 56 + sch]) = av;
        *reinterpret_cast<bf16x8*>(&sW[srow * 56 + sch]) = wv;
        __syncthreads();
        bf16x8 a0 = *reinterpret_cast<const bf16x8*>(&sA[(wr * 32 + nn) * 56 + g * 8]);
        bf16x8 a1 = *reinterpret_cast<const bf16x8*>(&sA[(wr * 32 + 16 + nn) * 56 + g * 8]);
        bf16x8 w0 = *reinterpret_cast<const bf16x8*>(&sW[(wc * 32 + nn) * 56 + g * 8]);
        bf16x8 w1 = *reinterpret_cast<const bf16x8*>(&sW[(wc * 32 + 16 + nn) * 56 + g * 8]);
        acc[0][0] = __builtin_amdgcn_mfma_f32_16x16x32_bf16(a0, w0, acc[0][0], 0, 0, 0);
        acc[0][1] = __builtin_amdgcn_mfma_f32_16x16x32_bf16(a0, w1, acc[0][1], 0, 0, 0);
        acc[1][0] = __builtin_amdgcn_mfma_f32_16x16x32_bf16(a1, w0, acc[1][0], 0, 0, 0);
        acc[1][1] = __builtin_amdgcn_mfma_f32_16x16x32_bf16(a1, w1, acc[1][1], 0, 0, 0);
    }
}

// ---------------------------------------------------------------------------
// Generic GEMM + epilogue. EPI: 0 none, 1 exact GELU, 2 +res (fp32).
// OUTBF: 1 -> bf16 out, 0 -> fp32 out.
// ---------------------------------------------------------------------------
template<int EPI, int OUTBF>
__global__ __launch_bounds__(256) void gemm_bf16(
    const ushort* __restrict__ A, const ushort* __restrict__ Wt,
    const float* __restrict__ bias, const float* __restrict__ res,
    void* __restrict__ Cout, int M, int N, int K)
{
    __shared__ __align__(16) ushort sA[64 * 56];
    __shared__ __align__(16) ushort sW[64 * 56];
    const int row0 = blockIdx.y * 64, col0 = blockIdx.x * 64;
    f32x4 acc[2][2] = {};
    gemm_core64(A, Wt, K, row0, col0, sA, sW, acc);

    const int lane = threadIdx.x & 63;
    const int wid  = threadIdx.x >> 6;
    const int wr = wid >> 1, wc = wid & 1;
    const int g = lane >> 4, nn = lane & 15;
#pragma unroll
    for (int mi = 0; mi < 2; ++mi)
#pragma unroll
    for (int ni = 0; ni < 2; ++ni)
#pragma unroll
    for (int r = 0; r < 4; ++r) {
        const int m = row0 + wr * 32 + mi * 16 + g * 4 + r;
        const int c = col0 + wc * 32 + ni * 16 + nn;
        float v = acc[mi][ni][r] + bias[c];
        if (EPI == 1) v = 0.5f * v * (1.0f + erff(v * 0.70710678118654752f));
        if (EPI == 2) v += res[(size_t)m * N + c];
        if (OUTBF) ((ushort*)Cout)[(size_t)m * N + c] = (ushort)f2bf(v);
        else       ((float*)Cout)[(size_t)m * N + c] = v;
    }
}

// ---------------------------------------------------------------------------
// Fused QKV GEMM: grid.x = 12 (0-3 Q, 4-7 K, 8-11 V), grid.y = 64.
// Q,K -> bf16 row-major [B,L,D]. V -> transposed Vt[b][h][d][l] bf16 so the
// attention V-fragments become contiguous b64 loads.
// ---------------------------------------------------------------------------
__global__ __launch_bounds__(256) void gemm_qkv(
    const ushort* __restrict__ A,
    const ushort* __restrict__ WqT, const ushort* __restrict__ WkT,
    const ushort* __restrict__ WvT,
    const float* __restrict__ bq, const float* __restrict__ bk,
    const float* __restrict__ bv,
    ushort* __restrict__ Qb, ushort* __restrict__ Kb, ushort* __restrict__ Vt)
{
    __shared__ __align__(16) ushort sA[64 * 56];
    __shared__ __align__(16) ushort sW[64 * 56];
    const int nb = blockIdx.x;
    const int wsel = nb >> 2;
    const int col0 = (nb & 3) * 64;
    const int row0 = blockIdx.y * 64;
    const ushort* Wt = (wsel == 0) ? WqT : (wsel == 1) ? WkT : WvT;
    const float* bias = (wsel == 0) ? bq : (wsel == 1) ? bk : bv;

    f32x4 acc[2][2] = {};
    gemm_core64(A, Wt, 256, row0, col0, sA, sW, acc);

    const int lane = threadIdx.x & 63;
    const int wid  = threadIdx.x >> 6;
    const int wr = wid >> 1, wc = wid & 1;
    const int g = lane >> 4, nn = lane & 15;
    ushort* QK = (wsel == 0) ? Qb : Kb;
#pragma unroll
    for (int mi = 0; mi < 2; ++mi)
#pragma unroll
    for (int ni = 0; ni < 2; ++ni)
#pragma unroll
    for (int r = 0; r < 4; ++r) {
        const int m = row0 + wr * 32 + mi * 16 + g * 4 + r;
        const int c = col0 + wc * 32 + ni * 16 + nn;
        const float v = acc[mi][ni][r] + bias[c];
        if (wsel < 2) {
            QK[(size_t)m * D_ + c] = (ushort)f2bf(v);
        } else {
            const int b = m >> 11, l = m & 2047;
            const int h = c >> 5,  d = c & 31;
            Vt[(size_t)((b * 8 + h) * 32 + d) * L_ + l] = (ushort)f2bf(v);
        }
    }
}

// ---------------------------------------------------------------------------
// LayerNorm over D=256 -> bf16 out. One block per row.
// ---------------------------------------------------------------------------
__global__ __launch_bounds__(256) void ln_kernel(
    const float* __restrict__ x, const float* __restrict__ g,
    const float* __restrict__ b, ushort* __restrict__ y)
{
    const int row = blockIdx.x;
    const int tid = threadIdx.x;
    const float v = x[row * D_ + tid];
    float s = v, s2 = v * v;
#pragma unroll
    for (int off = 32; off > 0; off >>= 1) {
        s  += __shfl_xor(s,  off);
        s2 += __shfl_xor(s2, off);
    }
    __shared__ float ls[4], ls2[4];
    const int wid = tid >> 6;
    if ((tid & 63) == 0) { ls[wid] = s; ls2[wid] = s2; }
    __syncthreads();
    s  = ls[0]  + ls[1]  + ls[2]  + ls[3];
    s2 = ls2[0] + ls2[1] + ls2[2] + ls2[3];
    const float m   = s * (1.0f / D_);
    const float var = s2 * (1.0f / D_) - m * m;
    const float r   = rsqrtf(var + 1e-5f);
    y[row * D_ + tid] = (ushort)f2bf((v - m) * r * g[tid] + b[tid]);
}

// ---------------------------------------------------------------------------
// MFMA evidence attention, bf16 operands. One wave per (bh, 16-query tile).
// Fragment maps identical to (verified) round 2; only the load paths changed:
//   Q/K: direct b128 bf16 loads. V: 4x b64 from transposed Vt.
// ---------------------------------------------------------------------------
__global__ __launch_bounds__(64) void attn_mfma(
    const ushort* __restrict__ Qb, const ushort* __restrict__ Kb,
    const ushort* __restrict__ Vt, ushort* __restrict__ O,
    float* __restrict__ unc, const float* __restrict__ ev_scale,
    const float* __restrict__ ev_bias, int layer)
{
    const int bh = blockIdx.y;
    const int b  = bh >> 3;
    const int h  = bh & 7;
    const int q0 = blockIdx.x * 16;
    const int lane = threadIdx.x;
    const int g = lane >> 4;
    const int n = lane & 15;
    const float scale = ev_scale[layer];
    const float cb    = 1.0f + ev_bias[layer];
    const float isq   = 0.17677669529663687f;   // 1/sqrt(32)

    const size_t qk0 = (size_t)b * L_ * D_ + h * HD_;
    const bf16x8 qf = *reinterpret_cast<const bf16x8*>(&Qb[qk0 + (size_t)(q0 + n) * D_ + g * 8]);
    const ushort* kb = &Kb[qk0 + g * 8];
    const ushort* v0 = &Vt[(size_t)((b * 8 + h) * 32 + n) * L_];        // d = n
    const ushort* v1 = v0 + (size_t)16 * L_;                            // d = n+16

    f32x4 acc0 = {0.f, 0.f, 0.f, 0.f};
    f32x4 acc1 = {0.f, 0.f, 0.f, 0.f};
    const f32x4 zero = {0.f, 0.f, 0.f, 0.f};
    float esum = 0.f;

    for (int t = 0; t < L_; t += 32) {
        bf16x8 kf0 = *reinterpret_cast<const bf16x8*>(kb + (size_t)(t + n) * D_);
        bf16x8 kf1 = *reinterpret_cast<const bf16x8*>(kb + (size_t)(t + 16 + n) * D_);

        f32x4 s0 = __builtin_amdgcn_mfma_f32_16x16x32_bf16(kf0, qf, zero, 0, 0, 0);
        f32x4 s1 = __builtin_amdgcn_mfma_f32_16x16x32_bf16(kf1, qf, zero, 0, 0, 0);

        short4 va = *reinterpret_cast<const short4*>(v0 + t + g * 4);
        short4 vb = *reinterpret_cast<const short4*>(v0 + t + 16 + g * 4);
        short4 vc = *reinterpret_cast<const short4*>(v1 + t + g * 4);
        short4 vd = *reinterpret_cast<const short4*>(v1 + t + 16 + g * 4);
        bf16x8 vf0 = {va.x, va.y, va.z, va.w, vb.x, vb.y, vb.z, vb.w};
        bf16x8 vf1 = {vc.x, vc.y, vc.z, vc.w, vd.x, vd.y, vd.z, vd.w};

        bf16x8 pa;
#pragma unroll
        for (int r = 0; r < 4; ++r) {
            float e = fmaf(__expf(s0[r] * isq), scale, cb);
            esum += e;
            pa[r] = f2bf(e);
        }
#pragma unroll
        for (int r = 0; r < 4; ++r) {
            float e = fmaf(__expf(s1[r] * isq), scale, cb);
            esum += e;
            pa[r + 4] = f2bf(e);
        }

        acc0 = __builtin_amdgcn_mfma_f32_16x16x32_bf16(vf0, pa, acc0, 0, 0, 0);
        acc1 = __builtin_amdgcn_mfma_f32_16x16x32_bf16(vf1, pa, acc1, 0, 0, 0);
    }

    esum += __shfl_xor(esum, 16);
    esum += __shfl_xor(esum, 32);
    const float inv = 1.0f / esum;

    ushort* op = &O[qk0 + (size_t)(q0 + n) * D_ + g * 4];
    short4 o0 = {f2bf(acc0[0] * inv), f2bf(acc0[1] * inv), f2bf(acc0[2] * inv), f2bf(acc0[3] * inv)};
    short4 o1 = {f2bf(acc1[0] * inv), f2bf(acc1[1] * inv), f2bf(acc1[2] * inv), f2bf(acc1[3] * inv)};
    *reinterpret_cast<short4*>(op)      = o0;
    *reinterpret_cast<short4*>(op + 16) = o1;

    if (g == 0) {
        const float u = (float)L_ * inv;
        const int uidx = bh * L_ + q0 + n;
        unc[uidx] = (layer == 0) ? u : (unc[uidx] + u);
    }
}

// ---------------------------------------------------------------------------
__global__ __launch_bounds__(256) void unc_final(
    const float* __restrict__ unc, float* __restrict__ out_unc,
    float* __restrict__ out_abst)
{
    const int i = blockIdx.x * 256 + threadIdx.x;
    const float u = unc[i] * 0.25f;
    out_unc[i]  = u;
    out_abst[i] = (u > 0.3f) ? 1.0f : 0.0f;
}

// ---------------------------------------------------------------------------
extern "C" void kernel_launch(void* const* d_in, const int* in_sizes, int n_in,
                              void* d_out, int out_size, void* d_ws, size_t ws_size,
                              hipStream_t stream)
{
    const float* x    = (const float*)d_in[0];
    const float* Win  = (const float*)d_in[1];
    const float* bin_ = (const float*)d_in[2];
    const float* Wq   = (const float*)d_in[3];
    const float* bq   = (const float*)d_in[4];
    const float* Wk   = (const float*)d_in[5];
    const float* bk   = (const float*)d_in[6];
    const float* Wv   = (const float*)d_in[7];
    const float* bv   = (const float*)d_in[8];
    const float* Wo   = (const float*)d_in[9];
    const float* bo   = (const float*)d_in[10];
    const float* evs  = (const float*)d_in[11];
    const float* evb  = (const float*)d_in[12];
    const float* W1   = (const float*)d_in[13];
    const float* b1   = (const float*)d_in[14];
    const float* W2   = (const float*)d_in[15];
    const float* b2   = (const float*)d_in[16];
    const float* n1g  = (const float*)d_in[17];
    const float* n1b  = (const float*)d_in[18];
    const float* n2g  = (const float*)d_in[19];
    const float* n2b  = (const float*)d_in[20];
    const float* fng  = (const float*)d_in[21];
    const float* fnb  = (const float*)d_in[22];
    const float* Wout = (const float*)d_in[23];
    const float* bout = (const float*)d_in[24];

    char* ws = (char*)d_ws;
    float*  h    = (float*) (ws);                  // 4 MB fp32 residual stream
    ushort* tmpb = (ushort*)(ws + (4  << 20));     // 2 MB bf16 (LN out / x-bf16)
    ushort* Qb   = (ushort*)(ws + (6  << 20));     // 2 MB
    ushort* Kb   = (ushort*)(ws + (8  << 20));     // 2 MB
    ushort* Vt   = (ushort*)(ws + (10 << 20));     // 2 MB (transposed V)
    ushort* Ob   = (ushort*)(ws + (12 << 20));     // 2 MB (attn out)
    ushort* ffb  = (ushort*)(ws + (6  << 20));     // 8 MB, overlays Qb..Ob (dead by FF1)
    float*  unc  = (float*) (ws + (14 << 20));     // 128 KB
    ushort* T    = (ushort*)(ws + (15 << 20));     // 6.55 MB transposed bf16 weights

    ushort* winT  = T;
    ushort* woutT = T + 65536 * 17 + 2097152;

    float* out_main = (float*)d_out;
    float* out_unc  = out_main + M_ * D_;
    float* out_abst = out_unc + B_ * H_ * L_;

    const dim3 blk(256);
    const dim3 g256(4, 64);     // N=256 GEMMs
    const dim3 g1024(16, 64);   // N=1024 GEMM
    const dim3 gqkv(12, 64);
    const dim3 gattn(L_ / 16, B_ * H_);

    transpose_weights<<<3200, blk, 0, stream>>>(Win, Wq, Wk, Wv, Wo, W1, W2, Wout, T);
    f32_to_bf16<<<1024, blk, 0, stream>>>(x, tmpb);
    gemm_bf16<0, 0><<<g256, blk, 0, stream>>>(tmpb, winT, bin_, nullptr, h, M_, D_, D_);

    for (int i = 0; i < LY_; ++i) {
        ushort* wqT = T + 65536 * (1 + i);
        ushort* wkT = T + 65536 * (5 + i);
        ushort* wvT = T + 65536 * (9 + i);
        ushort* woT = T + 65536 * (13 + i);
        ushort* w1T = T + 65536 * 17 + i * 262144;
        ushort* w2T = T + 65536 * 17 + 1048576 + i * 262144;

        ln_kernel<<<M_, blk, 0, stream>>>(h, n1g + i * D_, n1b + i * D_, tmpb);
        gemm_qkv<<<gqkv, blk, 0, stream>>>(tmpb, wqT, wkT, wvT,
                                           bq + i * D_, bk + i * D_, bv + i * D_,
                                           Qb, Kb, Vt);
        attn_mfma<<<gattn, 64, 0, stream>>>(Qb, Kb, Vt, Ob, unc, evs, evb, i);
        gemm_bf16<2, 0><<<g256, blk, 0, stream>>>(Ob, woT, bo + i * D_, h, h, M_, D_, D_);
        ln_kernel<<<M_, blk, 0, stream>>>(h, n2g + i * D_, n2b + i * D_, tmpb);
        gemm_bf16<1, 1><<<g1024, blk, 0, stream>>>(tmpb, w1T, b1 + i * F_, nullptr, ffb, M_, F_, D_);
        gemm_bf16<2, 0><<<g256, blk, 0, stream>>>(ffb, w2T, b2 + i * D_, h, h, M_, D_, F_);
    }

    ln_kernel<<<M_, blk, 0, stream>>>(h, fng, fnb, tmpb);
    gemm_bf16<0, 0><<<g256, blk, 0, stream>>>(tmpb, woutT, bout, nullptr, out_main, M_, D_, D_);
    unc_final<<<(B_ * H_ * L_) / 256, blk, 0, stream>>>(unc, out_unc, out_abst);
}

// Round 4
// 557.820 us; speedup vs baseline: 3.3541x; 1.0410x over previous
//
#include <hip/hip_runtime.h>
#include <hip/hip_bf16.h>
#include <math.h>

#define B_  2
#define L_  2048
#define D_  256
#define H_  8
#define HD_ 32
#define F_  1024
#define LY_ 4
#define M_  (B_*L_)

typedef __attribute__((ext_vector_type(8))) short bf16x8;   // 8 bf16 in 4 VGPRs
typedef __attribute__((ext_vector_type(4))) float f32x4;

static __device__ __forceinline__ short f2bf(float f) {
    return __builtin_bit_cast(short, __float2bfloat16(f));
}

// ---------------------------------------------------------------------------
// Weight transpose + fp32->bf16:  W[K][N] -> Wt[N][K] bf16  (unchanged)
// ---------------------------------------------------------------------------
__global__ __launch_bounds__(256) void transpose_weights(
    const float* __restrict__ Win, const float* __restrict__ Wq,
    const float* __restrict__ Wk,  const float* __restrict__ Wv,
    const float* __restrict__ Wo,  const float* __restrict__ W1,
    const float* __restrict__ W2,  const float* __restrict__ Wout,
    ushort* __restrict__ T)
{
    const int bid = blockIdx.x;
    const float* src; ushort* dst; int K, N, tt;
    if (bid < 64)        { src = Win; dst = T; K = 256; N = 256; tt = bid; }
    else if (bid < 1088) {
        int i = bid - 64; int which = i >> 8; int l = (i >> 6) & 3; tt = i & 63;
        K = 256; N = 256;
        const float* s4[4] = {Wq, Wk, Wv, Wo};
        src = s4[which] + l * 65536;
        dst = T + 65536 * (1 + which * 4 + l);
    } else if (bid < 2112) {
        int i = bid - 1088; int l = i >> 8; tt = i & 255; K = 256; N = 1024;
        src = W1 + l * 262144; dst = T + 65536 * 17 + l * 262144;
    } else if (bid < 3136) {
        int i = bid - 2112; int l = i >> 8; tt = i & 255; K = 1024; N = 256;
        src = W2 + l * 262144; dst = T + 65536 * 17 + 1048576 + l * 262144;
    } else {
        src = Wout; dst = T + 65536 * 17 + 2097152; K = 256; N = 256; tt = bid - 3136;
    }
    const int ntn = N >> 5;
    const int tk = tt / ntn, tn = tt % ntn;
    __shared__ float ld[32][33];
    const int t = threadIdx.x;
    const int r = t >> 3, c4 = (t & 7) * 4;
    float4 v = *reinterpret_cast<const float4*>(&src[(size_t)(tk * 32 + r) * N + tn * 32 + c4]);
    ld[r][c4 + 0] = v.x; ld[r][c4 + 1] = v.y; ld[r][c4 + 2] = v.z; ld[r][c4 + 3] = v.w;
    __syncthreads();
    short4 o;
    o.x = f2bf(ld[c4 + 0][r]);
    o.y = f2bf(ld[c4 + 1][r]);
    o.z = f2bf(ld[c4 + 2][r]);
    o.w = f2bf(ld[c4 + 3][r]);
    *reinterpret_cast<short4*>(&dst[(size_t)(tn * 32 + r) * K + tk * 32 + c4]) = o;
}

// ---------------------------------------------------------------------------
__global__ __launch_bounds__(256) void f32_to_bf16(
    const float* __restrict__ in, ushort* __restrict__ out)
{
    const int i = (blockIdx.x * 256 + threadIdx.x) * 4;
    float4 v = *reinterpret_cast<const float4*>(&in[i]);
    short4 o = {f2bf(v.x), f2bf(v.y), f2bf(v.z), f2bf(v.w)};
    *reinterpret_cast<short4*>(&out[i]) = o;
}

// ---------------------------------------------------------------------------
// bf16 MFMA GEMM core, BK=64: 4 waves (2x2), 2x2 16x16x32 frags per wave,
// 8 MFMAs per barrier pair. LDS rows 72 ushorts (144 B, 16B-aligned).
// ---------------------------------------------------------------------------
__device__ __forceinline__ void gemm_core64(
    const ushort* __restrict__ A, const ushort* __restrict__ Wt, int K,
    int row0, int col0, ushort* sA, ushort* sW, f32x4 acc[2][2])
{
    const int tid  = threadIdx.x;
    const int lane = tid & 63;
    const int wid  = tid >> 6;
    const int wr = wid >> 1, wc = wid & 1;
    const int g = lane >> 4, nn = lane & 15;
    const int srow = tid >> 2;          // 0..63
    const int sch  = (tid & 3) * 16;    // 0,16,32,48

    const ushort* Ap = &A[(size_t)(row0 + srow) * K + sch];
    const ushort* Wp = &Wt[(size_t)(col0 + srow) * K + sch];

    for (int k0 = 0; k0 < K; k0 += 64) {
        bf16x8 av0 = *reinterpret_cast<const bf16x8*>(Ap + k0);
        bf16x8 av1 = *reinterpret_cast<const bf16x8*>(Ap + k0 + 8);
        bf16x8 wv0 = *reinterpret_cast<const bf16x8*>(Wp + k0);
        bf16x8 wv1 = *reinterpret_cast<const bf16x8*>(Wp + k0 + 8);
        __syncthreads();
        *reinterpret_cast<bf16x8*>(&sA[srow * 72 + sch])     = av0;
        *reinterpret_cast<bf16x8*>(&sA[srow * 72 + sch + 8]) = av1;
        *reinterpret_cast<bf16x8*>(&sW[srow * 72 + sch])     = wv0;
        *reinterpret_cast<bf16x8*>(&sW[srow * 72 + sch + 8]) = wv1;
        __syncthreads();
#pragma unroll
        for (int s = 0; s < 2; ++s) {
            bf16x8 a0 = *reinterpret_cast<const bf16x8*>(&sA[(wr * 32 + nn) * 72 + s * 32 + g * 8]);
            bf16x8 a1 = *reinterpret_cast<const bf16x8*>(&sA[(wr * 32 + 16 + nn) * 72 + s * 32 + g * 8]);
            bf16x8 w0 = *reinterpret_cast<const bf16x8*>(&sW[(wc * 32 + nn) * 72 + s * 32 + g * 8]);
            bf16x8 w1 = *reinterpret_cast<const bf16x8*>(&sW[(wc * 32 + 16 + nn) * 72 + s * 32 + g * 8]);
            acc[0][0] = __builtin_amdgcn_mfma_f32_16x16x32_bf16(a0, w0, acc[0][0], 0, 0, 0);
            acc[0][1] = __builtin_amdgcn_mfma_f32_16x16x32_bf16(a0, w1, acc[0][1], 0, 0, 0);
            acc[1][0] = __builtin_amdgcn_mfma_f32_16x16x32_bf16(a1, w0, acc[1][0], 0, 0, 0);
            acc[1][1] = __builtin_amdgcn_mfma_f32_16x16x32_bf16(a1, w1, acc[1][1], 0, 0, 0);
        }
    }
}

// ---------------------------------------------------------------------------
// Generic GEMM + epilogue. EPI: 0 none, 1 exact GELU, 2 +res (fp32).
// ---------------------------------------------------------------------------
template<int EPI, int OUTBF>
__global__ __launch_bounds__(256) void gemm_bf16(
    const ushort* __restrict__ A, const ushort* __restrict__ Wt,
    const float* __restrict__ bias, const float* __restrict__ res,
    void* __restrict__ Cout, int M, int N, int K)
{
    __shared__ __align__(16) ushort sA[64 * 72];
    __shared__ __align__(16) ushort sW[64 * 72];
    const int row0 = blockIdx.y * 64, col0 = blockIdx.x * 64;
    f32x4 acc[2][2] = {};
    gemm_core64(A, Wt, K, row0, col0, sA, sW, acc);

    const int lane = threadIdx.x & 63;
    const int wid  = threadIdx.x >> 6;
    const int wr = wid >> 1, wc = wid & 1;
    const int g = lane >> 4, nn = lane & 15;
#pragma unroll
    for (int mi = 0; mi < 2; ++mi)
#pragma unroll
    for (int ni = 0; ni < 2; ++ni)
#pragma unroll
    for (int r = 0; r < 4; ++r) {
        const int m = row0 + wr * 32 + mi * 16 + g * 4 + r;
        const int c = col0 + wc * 32 + ni * 16 + nn;
        float v = acc[mi][ni][r] + bias[c];
        if (EPI == 1) v = 0.5f * v * (1.0f + erff(v * 0.70710678118654752f));
        if (EPI == 2) v += res[(size_t)m * N + c];
        if (OUTBF) ((ushort*)Cout)[(size_t)m * N + c] = (ushort)f2bf(v);
        else       ((float*)Cout)[(size_t)m * N + c] = v;
    }
}

// ---------------------------------------------------------------------------
// Fused QKV GEMM (unchanged epilogue; BK=64 core).
// ---------------------------------------------------------------------------
__global__ __launch_bounds__(256) void gemm_qkv(
    const ushort* __restrict__ A,
    const ushort* __restrict__ WqT, const ushort* __restrict__ WkT,
    const ushort* __restrict__ WvT,
    const float* __restrict__ bq, const float* __restrict__ bk,
    const float* __restrict__ bv,
    ushort* __restrict__ Qb, ushort* __restrict__ Kb, ushort* __restrict__ Vt)
{
    __shared__ __align__(16) ushort sA[64 * 72];
    __shared__ __align__(16) ushort sW[64 * 72];
    const int nb = blockIdx.x;
    const int wsel = nb >> 2;
    const int col0 = (nb & 3) * 64;
    const int row0 = blockIdx.y * 64;
    const ushort* Wt = (wsel == 0) ? WqT : (wsel == 1) ? WkT : WvT;
    const float* bias = (wsel == 0) ? bq : (wsel == 1) ? bk : bv;

    f32x4 acc[2][2] = {};
    gemm_core64(A, Wt, 256, row0, col0, sA, sW, acc);

    const int lane = threadIdx.x & 63;
    const int wid  = threadIdx.x >> 6;
    const int wr = wid >> 1, wc = wid & 1;
    const int g = lane >> 4, nn = lane & 15;
    ushort* QK = (wsel == 0) ? Qb : Kb;
#pragma unroll
    for (int mi = 0; mi < 2; ++mi)
#pragma unroll
    for (int ni = 0; ni < 2; ++ni)
#pragma unroll
    for (int r = 0; r < 4; ++r) {
        const int m = row0 + wr * 32 + mi * 16 + g * 4 + r;
        const int c = col0 + wc * 32 + ni * 16 + nn;
        const float v = acc[mi][ni][r] + bias[c];
        if (wsel < 2) {
            QK[(size_t)m * D_ + c] = (ushort)f2bf(v);
        } else {
            const int b = m >> 11, l = m & 2047;
            const int h = c >> 5,  d = c & 31;
            Vt[(size_t)((b * 8 + h) * 32 + d) * L_ + l] = (ushort)f2bf(v);
        }
    }
}

// ---------------------------------------------------------------------------
// LayerNorm over D=256 -> bf16 out. One block per row.  (unchanged)
// ---------------------------------------------------------------------------
__global__ __launch_bounds__(256) void ln_kernel(
    const float* __restrict__ x, const float* __restrict__ g,
    const float* __restrict__ b, ushort* __restrict__ y)
{
    const int row = blockIdx.x;
    const int tid = threadIdx.x;
    const float v = x[row * D_ + tid];
    float s = v, s2 = v * v;
#pragma unroll
    for (int off = 32; off > 0; off >>= 1) {
        s  += __shfl_xor(s,  off);
        s2 += __shfl_xor(s2, off);
    }
    __shared__ float ls[4], ls2[4];
    const int wid = tid >> 6;
    if ((tid & 63) == 0) { ls[wid] = s; ls2[wid] = s2; }
    __syncthreads();
    s  = ls[0]  + ls[1]  + ls[2]  + ls[3];
    s2 = ls2[0] + ls2[1] + ls2[2] + ls2[3];
    const float m   = s * (1.0f / D_);
    const float var = s2 * (1.0f / D_) - m * m;
    const float r   = rsqrtf(var + 1e-5f);
    y[row * D_ + tid] = (ushort)f2bf((v - m) * r * g[tid] + b[tid]);
}

// ---------------------------------------------------------------------------
// MFMA evidence attention, split-K over 4 waves.
// Block = 256 threads = 4 waves, one (bh, 16-query) tile; wave w owns keys
// [w*512, w*512+512). Inner body identical to the verified round-2/3 kernel.
// Per-lane partials (acc0,acc1,esum) are element-aligned across waves (same
// lane->(q,d) map), so combine = 9-float/lane LDS reduction by wave 0.
// ---------------------------------------------------------------------------
__global__ __launch_bounds__(256) void attn_mfma(
    const ushort* __restrict__ Qb, const ushort* __restrict__ Kb,
    const ushort* __restrict__ Vt, ushort* __restrict__ O,
    float* __restrict__ unc, const float* __restrict__ ev_scale,
    const float* __restrict__ ev_bias, int layer)
{
    const int bh = blockIdx.y;
    const int b  = bh >> 3;
    const int h  = bh & 7;
    const int q0 = blockIdx.x * 16;
    const int tid  = threadIdx.x;
    const int wv   = tid >> 6;          // wave 0..3: key range owner
    const int lane = tid & 63;
    const int g = lane >> 4;
    const int n = lane & 15;
    const float scale = ev_scale[layer];
    const float cb    = 1.0f + ev_bias[layer];
    const float isq   = 0.17677669529663687f;   // 1/sqrt(32)

    const size_t qk0 = (size_t)b * L_ * D_ + h * HD_;
    const bf16x8 qf = *reinterpret_cast<const bf16x8*>(&Qb[qk0 + (size_t)(q0 + n) * D_ + g * 8]);
    const ushort* kb = &Kb[qk0 + g * 8];
    const ushort* v0 = &Vt[(size_t)((b * 8 + h) * 32 + n) * L_];        // d = n
    const ushort* v1 = v0 + (size_t)16 * L_;                            // d = n+16

    f32x4 acc0 = {0.f, 0.f, 0.f, 0.f};
    f32x4 acc1 = {0.f, 0.f, 0.f, 0.f};
    const f32x4 zero = {0.f, 0.f, 0.f, 0.f};
    float esum = 0.f;

    const int t0 = wv * 512;
    for (int t = t0; t < t0 + 512; t += 32) {
        bf16x8 kf0 = *reinterpret_cast<const bf16x8*>(kb + (size_t)(t + n) * D_);
        bf16x8 kf1 = *reinterpret_cast<const bf16x8*>(kb + (size_t)(t + 16 + n) * D_);

        f32x4 s0 = __builtin_amdgcn_mfma_f32_16x16x32_bf16(kf0, qf, zero, 0, 0, 0);
        f32x4 s1 = __builtin_amdgcn_mfma_f32_16x16x32_bf16(kf1, qf, zero, 0, 0, 0);

        short4 va = *reinterpret_cast<const short4*>(v0 + t + g * 4);
        short4 vb = *reinterpret_cast<const short4*>(v0 + t + 16 + g * 4);
        short4 vc = *reinterpret_cast<const short4*>(v1 + t + g * 4);
        short4 vd = *reinterpret_cast<const short4*>(v1 + t + 16 + g * 4);
        bf16x8 vf0 = {va.x, va.y, va.z, va.w, vb.x, vb.y, vb.z, vb.w};
        bf16x8 vf1 = {vc.x, vc.y, vc.z, vc.w, vd.x, vd.y, vd.z, vd.w};

        bf16x8 pa;
#pragma unroll
        for (int r = 0; r < 4; ++r) {
            float e = fmaf(__expf(s0[r] * isq), scale, cb);
            esum += e;
            pa[r] = f2bf(e);
        }
#pragma unroll
        for (int r = 0; r < 4; ++r) {
            float e = fmaf(__expf(s1[r] * isq), scale, cb);
            esum += e;
            pa[r + 4] = f2bf(e);
        }

        acc0 = __builtin_amdgcn_mfma_f32_16x16x32_bf16(vf0, pa, acc0, 0, 0, 0);
        acc1 = __builtin_amdgcn_mfma_f32_16x16x32_bf16(vf1, pa, acc1, 0, 0, 0);
    }

    // ---- cross-wave combine: 9 floats per lane
    __shared__ float red[4][64][9];
#pragma unroll
    for (int r = 0; r < 4; ++r) { red[wv][lane][r] = acc0[r]; red[wv][lane][4 + r] = acc1[r]; }
    red[wv][lane][8] = esum;
    __syncthreads();

    if (wv == 0) {
#pragma unroll
        for (int w = 1; w < 4; ++w) {
#pragma unroll
            for (int r = 0; r < 4; ++r) { acc0[r] += red[w][lane][r]; acc1[r] += red[w][lane][4 + r]; }
            esum += red[w][lane][8];
        }
        esum += __shfl_xor(esum, 16);
        esum += __shfl_xor(esum, 32);
        const float inv = 1.0f / esum;

        ushort* op = &O[qk0 + (size_t)(q0 + n) * D_ + g * 4];
        short4 o0 = {f2bf(acc0[0] * inv), f2bf(acc0[1] * inv), f2bf(acc0[2] * inv), f2bf(acc0[3] * inv)};
        short4 o1 = {f2bf(acc1[0] * inv), f2bf(acc1[1] * inv), f2bf(acc1[2] * inv), f2bf(acc1[3] * inv)};
        *reinterpret_cast<short4*>(op)      = o0;
        *reinterpret_cast<short4*>(op + 16) = o1;

        if (g == 0) {
            const float u = (float)L_ * inv;
            const int uidx = bh * L_ + q0 + n;
            unc[uidx] = (layer == 0) ? u : (unc[uidx] + u);
        }
    }
}

// ---------------------------------------------------------------------------
__global__ __launch_bounds__(256) void unc_final(
    const float* __restrict__ unc, float* __restrict__ out_unc,
    float* __restrict__ out_abst)
{
    const int i = blockIdx.x * 256 + threadIdx.x;
    const float u = unc[i] * 0.25f;
    out_unc[i]  = u;
    out_abst[i] = (u > 0.3f) ? 1.0f : 0.0f;
}

// ---------------------------------------------------------------------------
extern "C" void kernel_launch(void* const* d_in, const int* in_sizes, int n_in,
                              void* d_out, int out_size, void* d_ws, size_t ws_size,
                              hipStream_t stream)
{
    const float* x    = (const float*)d_in[0];
    const float* Win  = (const float*)d_in[1];
    const float* bin_ = (const float*)d_in[2];
    const float* Wq   = (const float*)d_in[3];
    const float* bq   = (const float*)d_in[4];
    const float* Wk   = (const float*)d_in[5];
    const float* bk   = (const float*)d_in[6];
    const float* Wv   = (const float*)d_in[7];
    const float* bv   = (const float*)d_in[8];
    const float* Wo   = (const float*)d_in[9];
    const float* bo   = (const float*)d_in[10];
    const float* evs  = (const float*)d_in[11];
    const float* evb  = (const float*)d_in[12];
    const float* W1   = (const float*)d_in[13];
    const float* b1   = (const float*)d_in[14];
    const float* W2   = (const float*)d_in[15];
    const float* b2   = (const float*)d_in[16];
    const float* n1g  = (const float*)d_in[17];
    const float* n1b  = (const float*)d_in[18];
    const float* n2g  = (const float*)d_in[19];
    const float* n2b  = (const float*)d_in[20];
    const float* fng  = (const float*)d_in[21];
    const float* fnb  = (const float*)d_in[22];
    const float* Wout = (const float*)d_in[23];
    const float* bout = (const float*)d_in[24];

    char* ws = (char*)d_ws;
    float*  h    = (float*) (ws);                  // 4 MB fp32 residual stream
    ushort* tmpb = (ushort*)(ws + (4  << 20));     // 2 MB bf16 (LN out / x-bf16)
    ushort* Qb   = (ushort*)(ws + (6  << 20));     // 2 MB
    ushort* Kb   = (ushort*)(ws + (8  << 20));     // 2 MB
    ushort* Vt   = (ushort*)(ws + (10 << 20));     // 2 MB (transposed V)
    ushort* Ob   = (ushort*)(ws + (12 << 20));     // 2 MB (attn out)
    ushort* ffb  = (ushort*)(ws + (6  << 20));     // 8 MB, overlays Qb..Ob (dead by FF1)
    float*  unc  = (float*) (ws + (14 << 20));     // 128 KB
    ushort* T    = (ushort*)(ws + (15 << 20));     // 6.55 MB transposed bf16 weights

    ushort* winT  = T;
    ushort* woutT = T + 65536 * 17 + 2097152;

    float* out_main = (float*)d_out;
    float* out_unc  = out_main + M_ * D_;
    float* out_abst = out_unc + B_ * H_ * L_;

    const dim3 blk(256);
    const dim3 g256(4, 64);     // N=256 GEMMs
    const dim3 g1024(16, 64);   // N=1024 GEMM
    const dim3 gqkv(12, 64);
    const dim3 gattn(L_ / 16, B_ * H_);

    transpose_weights<<<3200, blk, 0, stream>>>(Win, Wq, Wk, Wv, Wo, W1, W2, Wout, T);
    f32_to_bf16<<<1024, blk, 0, stream>>>(x, tmpb);
    gemm_bf16<0, 0><<<g256, blk, 0, stream>>>(tmpb, winT, bin_, nullptr, h, M_, D_, D_);

    for (int i = 0; i < LY_; ++i) {
        ushort* wqT = T + 65536 * (1 + i);
        ushort* wkT = T + 65536 * (5 + i);
        ushort* wvT = T + 65536 * (9 + i);
        ushort* woT = T + 65536 * (13 + i);
        ushort* w1T = T + 65536 * 17 + i * 262144;
        ushort* w2T = T + 65536 * 17 + 1048576 + i * 262144;

        ln_kernel<<<M_, blk, 0, stream>>>(h, n1g + i * D_, n1b + i * D_, tmpb);
        gemm_qkv<<<gqkv, blk, 0, stream>>>(tmpb, wqT, wkT, wvT,
                                           bq + i * D_, bk + i * D_, bv + i * D_,
                                           Qb, Kb, Vt);
        attn_mfma<<<gattn, blk, 0, stream>>>(Qb, Kb, Vt, Ob, unc, evs, evb, i);
        gemm_bf16<2, 0><<<g256, blk, 0, stream>>>(Ob, woT, bo + i * D_, h, h, M_, D_, D_);
        ln_kernel<<<M_, blk, 0, stream>>>(h, n2g + i * D_, n2b + i * D_, tmpb);
        gemm_bf16<1, 1><<<g1024, blk, 0, stream>>>(tmpb, w1T, b1 + i * F_, nullptr, ffb, M_, F_, D_);
        gemm_bf16<2, 0><<<g256, blk, 0, stream>>>(ffb, w2T, b2 + i * D_, h, h, M_, D_, F_);
    }

    ln_kernel<<<M_, blk, 0, stream>>>(h, fng, fnb, tmpb);
    gemm_bf16<0, 0><<<g256, blk, 0, stream>>>(tmpb, woutT, bout, nullptr, out_main, M_, D_, D_);
    unc_final<<<(B_ * H_ * L_) / 256, blk, 0, stream>>>(unc, out_unc, out_abst);
}

// Round 5
// 312.106 us; speedup vs baseline: 5.9947x; 1.7873x over previous
//
#include <hip/hip_runtime.h>
#include <hip/hip_bf16.h>
#include <math.h>

#define B_  2
#define L_  2048
#define D_  256
#define H_  8
#define HD_ 32
#define F_  1024
#define LY_ 4
#define M_  (B_*L_)

typedef __attribute__((ext_vector_type(8))) short bf16x8;   // 8 bf16 in 4 VGPRs
typedef __attribute__((ext_vector_type(4))) float f32x4;

static __device__ __forceinline__ short f2bf(float f) {
    return __builtin_bit_cast(short, __float2bfloat16(f));
}

// ---------------------------------------------------------------------------
// Weight transpose + fp32->bf16:  W[K][N] -> Wt[N][K] bf16  (unchanged)
// ---------------------------------------------------------------------------
__global__ __launch_bounds__(256) void transpose_weights(
    const float* __restrict__ Win, const float* __restrict__ Wq,
    const float* __restrict__ Wk,  const float* __restrict__ Wv,
    const float* __restrict__ Wo,  const float* __restrict__ W1,
    const float* __restrict__ W2,  const float* __restrict__ Wout,
    ushort* __restrict__ T)
{
    const int bid = blockIdx.x;
    const float* src; ushort* dst; int K, N, tt;
    if (bid < 64)        { src = Win; dst = T; K = 256; N = 256; tt = bid; }
    else if (bid < 1088) {
        int i = bid - 64; int which = i >> 8; int l = (i >> 6) & 3; tt = i & 63;
        K = 256; N = 256;
        const float* s4[4] = {Wq, Wk, Wv, Wo};
        src = s4[which] + l * 65536;
        dst = T + 65536 * (1 + which * 4 + l);
    } else if (bid < 2112) {
        int i = bid - 1088; int l = i >> 8; tt = i & 255; K = 256; N = 1024;
        src = W1 + l * 262144; dst = T + 65536 * 17 + l * 262144;
    } else if (bid < 3136) {
        int i = bid - 2112; int l = i >> 8; tt = i & 255; K = 1024; N = 256;
        src = W2 + l * 262144; dst = T + 65536 * 17 + 1048576 + l * 262144;
    } else {
        src = Wout; dst = T + 65536 * 17 + 2097152; K = 256; N = 256; tt = bid - 3136;
    }
    const int ntn = N >> 5;
    const int tk = tt / ntn, tn = tt % ntn;
    __shared__ float ld[32][33];
    const int t = threadIdx.x;
    const int r = t >> 3, c4 = (t & 7) * 4;
    float4 v = *reinterpret_cast<const float4*>(&src[(size_t)(tk * 32 + r) * N + tn * 32 + c4]);
    ld[r][c4 + 0] = v.x; ld[r][c4 + 1] = v.y; ld[r][c4 + 2] = v.z; ld[r][c4 + 3] = v.w;
    __syncthreads();
    short4 o;
    o.x = f2bf(ld[c4 + 0][r]);
    o.y = f2bf(ld[c4 + 1][r]);
    o.z = f2bf(ld[c4 + 2][r]);
    o.w = f2bf(ld[c4 + 3][r]);
    *reinterpret_cast<short4*>(&dst[(size_t)(tn * 32 + r) * K + tk * 32 + c4]) = o;
}

// ---------------------------------------------------------------------------
__global__ __launch_bounds__(256) void f32_to_bf16(
    const float* __restrict__ in, ushort* __restrict__ out)
{
    const int i = (blockIdx.x * 256 + threadIdx.x) * 4;
    float4 v = *reinterpret_cast<const float4*>(&in[i]);
    short4 o = {f2bf(v.x), f2bf(v.y), f2bf(v.z), f2bf(v.w)};
    *reinterpret_cast<short4*>(&out[i]) = o;
}

// ---------------------------------------------------------------------------
// bf16 MFMA GEMM core, BK=64 (unchanged from round 4).
// ---------------------------------------------------------------------------
__device__ __forceinline__ void gemm_core64(
    const ushort* __restrict__ A, const ushort* __restrict__ Wt, int K,
    int row0, int col0, ushort* sA, ushort* sW, f32x4 acc[2][2])
{
    const int tid  = threadIdx.x;
    const int lane = tid & 63;
    const int wid  = tid >> 6;
    const int wr = wid >> 1, wc = wid & 1;
    const int g = lane >> 4, nn = lane & 15;
    const int srow = tid >> 2;          // 0..63
    const int sch  = (tid & 3) * 16;    // 0,16,32,48

    const ushort* Ap = &A[(size_t)(row0 + srow) * K + sch];
    const ushort* Wp = &Wt[(size_t)(col0 + srow) * K + sch];

    for (int k0 = 0; k0 < K; k0 += 64) {
        bf16x8 av0 = *reinterpret_cast<const bf16x8*>(Ap + k0);
        bf16x8 av1 = *reinterpret_cast<const bf16x8*>(Ap + k0 + 8);
        bf16x8 wv0 = *reinterpret_cast<const bf16x8*>(Wp + k0);
        bf16x8 wv1 = *reinterpret_cast<const bf16x8*>(Wp + k0 + 8);
        __syncthreads();
        *reinterpret_cast<bf16x8*>(&sA[srow * 72 + sch])     = av0;
        *reinterpret_cast<bf16x8*>(&sA[srow * 72 + sch + 8]) = av1;
        *reinterpret_cast<bf16x8*>(&sW[srow * 72 + sch])     = wv0;
        *reinterpret_cast<bf16x8*>(&sW[srow * 72 + sch + 8]) = wv1;
        __syncthreads();
#pragma unroll
        for (int s = 0; s < 2; ++s) {
            bf16x8 a0 = *reinterpret_cast<const bf16x8*>(&sA[(wr * 32 + nn) * 72 + s * 32 + g * 8]);
            bf16x8 a1 = *reinterpret_cast<const bf16x8*>(&sA[(wr * 32 + 16 + nn) * 72 + s * 32 + g * 8]);
            bf16x8 w0 = *reinterpret_cast<const bf16x8*>(&sW[(wc * 32 + nn) * 72 + s * 32 + g * 8]);
            bf16x8 w1 = *reinterpret_cast<const bf16x8*>(&sW[(wc * 32 + 16 + nn) * 72 + s * 32 + g * 8]);
            acc[0][0] = __builtin_amdgcn_mfma_f32_16x16x32_bf16(a0, w0, acc[0][0], 0, 0, 0);
            acc[0][1] = __builtin_amdgcn_mfma_f32_16x16x32_bf16(a0, w1, acc[0][1], 0, 0, 0);
            acc[1][0] = __builtin_amdgcn_mfma_f32_16x16x32_bf16(a1, w0, acc[1][0], 0, 0, 0);
            acc[1][1] = __builtin_amdgcn_mfma_f32_16x16x32_bf16(a1, w1, acc[1][1], 0, 0, 0);
        }
    }
}

// ---------------------------------------------------------------------------
// Generic GEMM + epilogue. EPI: 0 none, 1 exact GELU, 2 +res (fp32).
// ---------------------------------------------------------------------------
template<int EPI, int OUTBF>
__global__ __launch_bounds__(256) void gemm_bf16(
    const ushort* __restrict__ A, const ushort* __restrict__ Wt,
    const float* __restrict__ bias, const float* __restrict__ res,
    void* __restrict__ Cout, int M, int N, int K)
{
    __shared__ __align__(16) ushort sA[64 * 72];
    __shared__ __align__(16) ushort sW[64 * 72];
    const int row0 = blockIdx.y * 64, col0 = blockIdx.x * 64;
    f32x4 acc[2][2] = {};
    gemm_core64(A, Wt, K, row0, col0, sA, sW, acc);

    const int lane = threadIdx.x & 63;
    const int wid  = threadIdx.x >> 6;
    const int wr = wid >> 1, wc = wid & 1;
    const int g = lane >> 4, nn = lane & 15;
#pragma unroll
    for (int mi = 0; mi < 2; ++mi)
#pragma unroll
    for (int ni = 0; ni < 2; ++ni)
#pragma unroll
    for (int r = 0; r < 4; ++r) {
        const int m = row0 + wr * 32 + mi * 16 + g * 4 + r;
        const int c = col0 + wc * 32 + ni * 16 + nn;
        float v = acc[mi][ni][r] + bias[c];
        if (EPI == 1) v = 0.5f * v * (1.0f + erff(v * 0.70710678118654752f));
        if (EPI == 2) v += res[(size_t)m * N + c];
        if (OUTBF) ((ushort*)Cout)[(size_t)m * N + c] = (ushort)f2bf(v);
        else       ((float*)Cout)[(size_t)m * N + c] = v;
    }
}

// ---------------------------------------------------------------------------
// Fused QKV GEMM (unchanged).
// ---------------------------------------------------------------------------
__global__ __launch_bounds__(256) void gemm_qkv(
    const ushort* __restrict__ A,
    const ushort* __restrict__ WqT, const ushort* __restrict__ WkT,
    const ushort* __restrict__ WvT,
    const float* __restrict__ bq, const float* __restrict__ bk,
    const float* __restrict__ bv,
    ushort* __restrict__ Qb, ushort* __restrict__ Kb, ushort* __restrict__ Vt)
{
    __shared__ __align__(16) ushort sA[64 * 72];
    __shared__ __align__(16) ushort sW[64 * 72];
    const int nb = blockIdx.x;
    const int wsel = nb >> 2;
    const int col0 = (nb & 3) * 64;
    const int row0 = blockIdx.y * 64;
    const ushort* Wt = (wsel == 0) ? WqT : (wsel == 1) ? WkT : WvT;
    const float* bias = (wsel == 0) ? bq : (wsel == 1) ? bk : bv;

    f32x4 acc[2][2] = {};
    gemm_core64(A, Wt, 256, row0, col0, sA, sW, acc);

    const int lane = threadIdx.x & 63;
    const int wid  = threadIdx.x >> 6;
    const int wr = wid >> 1, wc = wid & 1;
    const int g = lane >> 4, nn = lane & 15;
    ushort* QK = (wsel == 0) ? Qb : Kb;
#pragma unroll
    for (int mi = 0; mi < 2; ++mi)
#pragma unroll
    for (int ni = 0; ni < 2; ++ni)
#pragma unroll
    for (int r = 0; r < 4; ++r) {
        const int m = row0 + wr * 32 + mi * 16 + g * 4 + r;
        const int c = col0 + wc * 32 + ni * 16 + nn;
        const float v = acc[mi][ni][r] + bias[c];
        if (wsel < 2) {
            QK[(size_t)m * D_ + c] = (ushort)f2bf(v);
        } else {
            const int b = m >> 11, l = m & 2047;
            const int h = c >> 5,  d = c & 31;
            Vt[(size_t)((b * 8 + h) * 32 + d) * L_ + l] = (ushort)f2bf(v);
        }
    }
}

// ---------------------------------------------------------------------------
// LayerNorm over D=256 -> bf16 out. One block per row.  (unchanged)
// ---------------------------------------------------------------------------
__global__ __launch_bounds__(256) void ln_kernel(
    const float* __restrict__ x, const float* __restrict__ g,
    const float* __restrict__ b, ushort* __restrict__ y)
{
    const int row = blockIdx.x;
    const int tid = threadIdx.x;
    const float v = x[row * D_ + tid];
    float s = v, s2 = v * v;
#pragma unroll
    for (int off = 32; off > 0; off >>= 1) {
        s  += __shfl_xor(s,  off);
        s2 += __shfl_xor(s2, off);
    }
    __shared__ float ls[4], ls2[4];
    const int wid = tid >> 6;
    if ((tid & 63) == 0) { ls[wid] = s; ls2[wid] = s2; }
    __syncthreads();
    s  = ls[0]  + ls[1]  + ls[2]  + ls[3];
    s2 = ls2[0] + ls2[1] + ls2[2] + ls2[3];
    const float m   = s * (1.0f / D_);
    const float var = s2 * (1.0f / D_) - m * m;
    const float r   = rsqrtf(var + 1e-5f);
    y[row * D_ + tid] = (ushort)f2bf((v - m) * r * g[tid] + b[tid]);
}

// ---------------------------------------------------------------------------
// MFMA evidence attention v5: LDS-staged K/V, Q-tile = 64 per block.
// Block = 256 threads = 4 waves; wave w owns queries [q0+w*16, q0+w*16+16).
// Loop over 2048 keys in KVBLK=64 tiles: stage K-tile [64][32] and V-tile
// (from transposed Vt) [32][64] into LDS with coalesced 16B/lane loads,
// double-buffered, ONE barrier per tile; next tile's global loads issued
// before the barrier so HBM/L2 latency hides under MFMA+exp.
// Inner fragment math identical to verified rounds 2-4.
// ---------------------------------------------------------------------------
__global__ __launch_bounds__(256) void attn_mfma(
    const ushort* __restrict__ Qb, const ushort* __restrict__ Kb,
    const ushort* __restrict__ Vt, ushort* __restrict__ O,
    float* __restrict__ unc, const float* __restrict__ ev_scale,
    const float* __restrict__ ev_bias, int layer)
{
    const int bh = blockIdx.y;
    const int b  = bh >> 3;
    const int h  = bh & 7;
    const int tid  = threadIdx.x;
    const int wv   = tid >> 6;
    const int lane = tid & 63;
    const int g = lane >> 4;
    const int n = lane & 15;
    const int q  = blockIdx.x * 64 + wv * 16 + n;
    const float scale = ev_scale[layer];
    const float cb    = 1.0f + ev_bias[layer];
    const float isq   = 0.17677669529663687f;   // 1/sqrt(32)

    // LDS: K-tile [64 keys][32 d] rows padded to 40 shorts (80B, 16B-aligned,
    // 2-way banks on b128 reads = free). V-tile [32 d][64 keys] rows padded
    // to 72 shorts (144B, 16B-aligned).
    __shared__ __align__(16) ushort sK[2][64][40];
    __shared__ __align__(16) ushort sV[2][32][72];

    const size_t qk0 = (size_t)b * L_ * D_ + h * HD_;
    const bf16x8 qf = *reinterpret_cast<const bf16x8*>(&Qb[qk0 + (size_t)q * D_ + g * 8]);

    // staging source pointers (16B per thread per buffer)
    const int krow = tid >> 2, kch = (tid & 3) * 8;   // K: 64 rows x 4 chunks
    const int vrow = tid >> 3, vch = (tid & 7) * 8;   // V: 32 rows x 8 chunks
    const ushort* ksrc = Kb + qk0 + (size_t)krow * D_ + kch;          // + t*D_
    const ushort* vsrc = Vt + (size_t)((b * 8 + h) * 32 + vrow) * L_ + vch;  // + t

    f32x4 acc0 = {0.f, 0.f, 0.f, 0.f};
    f32x4 acc1 = {0.f, 0.f, 0.f, 0.f};
    const f32x4 zero = {0.f, 0.f, 0.f, 0.f};
    float esum = 0.f;

    // prologue: load tile 0 into registers
    bf16x8 kreg = *reinterpret_cast<const bf16x8*>(ksrc);
    bf16x8 vreg = *reinterpret_cast<const bf16x8*>(vsrc);

    int cur = 0;
    for (int t = 0; t < L_; t += 64) {
        // write staged regs -> LDS[cur]; safe: all waves passed barrier(t-64),
        // which followed their consume of LDS[cur] at t-128.
        *reinterpret_cast<bf16x8*>(&sK[cur][krow][kch]) = kreg;
        *reinterpret_cast<bf16x8*>(&sV[cur][vrow][vch]) = vreg;
        // issue next tile's global loads early (hide under compute)
        if (t + 64 < L_) {
            kreg = *reinterpret_cast<const bf16x8*>(ksrc + (size_t)(t + 64) * D_);
            vreg = *reinterpret_cast<const bf16x8*>(vsrc + (t + 64));
        }
        __syncthreads();

#pragma unroll
        for (int tt = 0; tt < 64; tt += 32) {
            bf16x8 kf0 = *reinterpret_cast<const bf16x8*>(&sK[cur][tt + n][g * 8]);
            bf16x8 kf1 = *reinterpret_cast<const bf16x8*>(&sK[cur][tt + 16 + n][g * 8]);

            f32x4 s0 = __builtin_amdgcn_mfma_f32_16x16x32_bf16(kf0, qf, zero, 0, 0, 0);
            f32x4 s1 = __builtin_amdgcn_mfma_f32_16x16x32_bf16(kf1, qf, zero, 0, 0, 0);

            short4 va = *reinterpret_cast<const short4*>(&sV[cur][n][tt + g * 4]);
            short4 vb = *reinterpret_cast<const short4*>(&sV[cur][n][tt + 16 + g * 4]);
            short4 vc = *reinterpret_cast<const short4*>(&sV[cur][n + 16][tt + g * 4]);
            short4 vd = *reinterpret_cast<const short4*>(&sV[cur][n + 16][tt + 16 + g * 4]);
            bf16x8 vf0 = {va.x, va.y, va.z, va.w, vb.x, vb.y, vb.z, vb.w};
            bf16x8 vf1 = {vc.x, vc.y, vc.z, vc.w, vd.x, vd.y, vd.z, vd.w};

            bf16x8 pa;
#pragma unroll
            for (int r = 0; r < 4; ++r) {
                float e = fmaf(__expf(s0[r] * isq), scale, cb);
                esum += e;
                pa[r] = f2bf(e);
            }
#pragma unroll
            for (int r = 0; r < 4; ++r) {
                float e = fmaf(__expf(s1[r] * isq), scale, cb);
                esum += e;
                pa[r + 4] = f2bf(e);
            }

            acc0 = __builtin_amdgcn_mfma_f32_16x16x32_bf16(vf0, pa, acc0, 0, 0, 0);
            acc1 = __builtin_amdgcn_mfma_f32_16x16x32_bf16(vf1, pa, acc1, 0, 0, 0);
        }
        cur ^= 1;
    }

    esum += __shfl_xor(esum, 16);
    esum += __shfl_xor(esum, 32);
    const float inv = 1.0f / esum;

    ushort* op = &O[qk0 + (size_t)q * D_ + g * 4];
    short4 o0 = {f2bf(acc0[0] * inv), f2bf(acc0[1] * inv), f2bf(acc0[2] * inv), f2bf(acc0[3] * inv)};
    short4 o1 = {f2bf(acc1[0] * inv), f2bf(acc1[1] * inv), f2bf(acc1[2] * inv), f2bf(acc1[3] * inv)};
    *reinterpret_cast<short4*>(op)      = o0;
    *reinterpret_cast<short4*>(op + 16) = o1;

    if (g == 0) {
        const float u = (float)L_ * inv;
        const int uidx = bh * L_ + q;
        unc[uidx] = (layer == 0) ? u : (unc[uidx] + u);
    }
}

// ---------------------------------------------------------------------------
__global__ __launch_bounds__(256) void unc_final(
    const float* __restrict__ unc, float* __restrict__ out_unc,
    float* __restrict__ out_abst)
{
    const int i = blockIdx.x * 256 + threadIdx.x;
    const float u = unc[i] * 0.25f;
    out_unc[i]  = u;
    out_abst[i] = (u > 0.3f) ? 1.0f : 0.0f;
}

// ---------------------------------------------------------------------------
extern "C" void kernel_launch(void* const* d_in, const int* in_sizes, int n_in,
                              void* d_out, int out_size, void* d_ws, size_t ws_size,
                              hipStream_t stream)
{
    const float* x    = (const float*)d_in[0];
    const float* Win  = (const float*)d_in[1];
    const float* bin_ = (const float*)d_in[2];
    const float* Wq   = (const float*)d_in[3];
    const float* bq   = (const float*)d_in[4];
    const float* Wk   = (const float*)d_in[5];
    const float* bk   = (const float*)d_in[6];
    const float* Wv   = (const float*)d_in[7];
    const float* bv   = (const float*)d_in[8];
    const float* Wo   = (const float*)d_in[9];
    const float* bo   = (const float*)d_in[10];
    const float* evs  = (const float*)d_in[11];
    const float* evb  = (const float*)d_in[12];
    const float* W1   = (const float*)d_in[13];
    const float* b1   = (const float*)d_in[14];
    const float* W2   = (const float*)d_in[15];
    const float* b2   = (const float*)d_in[16];
    const float* n1g  = (const float*)d_in[17];
    const float* n1b  = (const float*)d_in[18];
    const float* n2g  = (const float*)d_in[19];
    const float* n2b  = (const float*)d_in[20];
    const float* fng  = (const float*)d_in[21];
    const float* fnb  = (const float*)d_in[22];
    const float* Wout = (const float*)d_in[23];
    const float* bout = (const float*)d_in[24];

    char* ws = (char*)d_ws;
    float*  h    = (float*) (ws);                  // 4 MB fp32 residual stream
    ushort* tmpb = (ushort*)(ws + (4  << 20));     // 2 MB bf16 (LN out / x-bf16)
    ushort* Qb   = (ushort*)(ws + (6  << 20));     // 2 MB
    ushort* Kb   = (ushort*)(ws + (8  << 20));     // 2 MB
    ushort* Vt   = (ushort*)(ws + (10 << 20));     // 2 MB (transposed V)
    ushort* Ob   = (ushort*)(ws + (12 << 20));     // 2 MB (attn out)
    ushort* ffb  = (ushort*)(ws + (6  << 20));     // 8 MB, overlays Qb..Ob (dead by FF1)
    float*  unc  = (float*) (ws + (14 << 20));     // 128 KB
    ushort* T    = (ushort*)(ws + (15 << 20));     // 6.55 MB transposed bf16 weights

    ushort* winT  = T;
    ushort* woutT = T + 65536 * 17 + 2097152;

    float* out_main = (float*)d_out;
    float* out_unc  = out_main + M_ * D_;
    float* out_abst = out_unc + B_ * H_ * L_;

    const dim3 blk(256);
    const dim3 g256(4, 64);     // N=256 GEMMs
    const dim3 g1024(16, 64);   // N=1024 GEMM
    const dim3 gqkv(12, 64);
    const dim3 gattn(L_ / 64, B_ * H_);

    transpose_weights<<<3200, blk, 0, stream>>>(Win, Wq, Wk, Wv, Wo, W1, W2, Wout, T);
    f32_to_bf16<<<1024, blk, 0, stream>>>(x, tmpb);
    gemm_bf16<0, 0><<<g256, blk, 0, stream>>>(tmpb, winT, bin_, nullptr, h, M_, D_, D_);

    for (int i = 0; i < LY_; ++i) {
        ushort* wqT = T + 65536 * (1 + i);
        ushort* wkT = T + 65536 * (5 + i);
        ushort* wvT = T + 65536 * (9 + i);
        ushort* woT = T + 65536 * (13 + i);
        ushort* w1T = T + 65536 * 17 + i * 262144;
        ushort* w2T = T + 65536 * 17 + 1048576 + i * 262144;

        ln_kernel<<<M_, blk, 0, stream>>>(h, n1g + i * D_, n1b + i * D_, tmpb);
        gemm_qkv<<<gqkv, blk, 0, stream>>>(tmpb, wqT, wkT, wvT,
                                           bq + i * D_, bk + i * D_, bv + i * D_,
                                           Qb, Kb, Vt);
        attn_mfma<<<gattn, blk, 0, stream>>>(Qb, Kb, Vt, Ob, unc, evs, evb, i);
        gemm_bf16<2, 0><<<g256, blk, 0, stream>>>(Ob, woT, bo + i * D_, h, h, M_, D_, D_);
        ln_kernel<<<M_, blk, 0, stream>>>(h, n2g + i * D_, n2b + i * D_, tmpb);
        gemm_bf16<1, 1><<<g1024, blk, 0, stream>>>(tmpb, w1T, b1 + i * F_, nullptr, ffb, M_, F_, D_);
        gemm_bf16<2, 0><<<g256, blk, 0, stream>>>(ffb, w2T, b2 + i * D_, h, h, M_, D_, F_);
    }

    ln_kernel<<<M_, blk, 0, stream>>>(h, fng, fnb, tmpb);
    gemm_bf16<0, 0><<<g256, blk, 0, stream>>>(tmpb, woutT, bout, nullptr, out_main, M_, D_, D_);
    unc_final<<<(B_ * H_ * L_) / 256, blk, 0, stream>>>(unc, out_unc, out_abst);
}

// Round 6
// 301.539 us; speedup vs baseline: 6.2048x; 1.0350x over previous
//
#include <hip/hip_runtime.h>
#include <hip/hip_bf16.h>
#include <math.h>

#define B_  2
#define L_  2048
#define D_  256
#define H_  8
#define HD_ 32
#define F_  1024
#define LY_ 4
#define M_  (B_*L_)

typedef __attribute__((ext_vector_type(8))) short bf16x8;   // 8 bf16 in 4 VGPRs
typedef __attribute__((ext_vector_type(4))) float f32x4;

static __device__ __forceinline__ short f2bf(float f) {
    return __builtin_bit_cast(short, __float2bfloat16(f));
}

static __device__ __forceinline__ void gload_lds16(const ushort* g, ushort* l) {
    __builtin_amdgcn_global_load_lds(
        (const __attribute__((address_space(1))) void*)g,
        (__attribute__((address_space(3))) void*)l, 16, 0, 0);
}

// ---------------------------------------------------------------------------
// Weight transpose + fp32->bf16:  W[K][N] -> Wt[N][K] bf16  (unchanged)
// ---------------------------------------------------------------------------
__global__ __launch_bounds__(256) void transpose_weights(
    const float* __restrict__ Win, const float* __restrict__ Wq,
    const float* __restrict__ Wk,  const float* __restrict__ Wv,
    const float* __restrict__ Wo,  const float* __restrict__ W1,
    const float* __restrict__ W2,  const float* __restrict__ Wout,
    ushort* __restrict__ T)
{
    const int bid = blockIdx.x;
    const float* src; ushort* dst; int K, N, tt;
    if (bid < 64)        { src = Win; dst = T; K = 256; N = 256; tt = bid; }
    else if (bid < 1088) {
        int i = bid - 64; int which = i >> 8; int l = (i >> 6) & 3; tt = i & 63;
        K = 256; N = 256;
        const float* s4[4] = {Wq, Wk, Wv, Wo};
        src = s4[which] + l * 65536;
        dst = T + 65536 * (1 + which * 4 + l);
    } else if (bid < 2112) {
        int i = bid - 1088; int l = i >> 8; tt = i & 255; K = 256; N = 1024;
        src = W1 + l * 262144; dst = T + 65536 * 17 + l * 262144;
    } else if (bid < 3136) {
        int i = bid - 2112; int l = i >> 8; tt = i & 255; K = 1024; N = 256;
        src = W2 + l * 262144; dst = T + 65536 * 17 + 1048576 + l * 262144;
    } else {
        src = Wout; dst = T + 65536 * 17 + 2097152; K = 256; N = 256; tt = bid - 3136;
    }
    const int ntn = N >> 5;
    const int tk = tt / ntn, tn = tt % ntn;
    __shared__ float ld[32][33];
    const int t = threadIdx.x;
    const int r = t >> 3, c4 = (t & 7) * 4;
    float4 v = *reinterpret_cast<const float4*>(&src[(size_t)(tk * 32 + r) * N + tn * 32 + c4]);
    ld[r][c4 + 0] = v.x; ld[r][c4 + 1] = v.y; ld[r][c4 + 2] = v.z; ld[r][c4 + 3] = v.w;
    __syncthreads();
    short4 o;
    o.x = f2bf(ld[c4 + 0][r]);
    o.y = f2bf(ld[c4 + 1][r]);
    o.z = f2bf(ld[c4 + 2][r]);
    o.w = f2bf(ld[c4 + 3][r]);
    *reinterpret_cast<short4*>(&dst[(size_t)(tn * 32 + r) * K + tk * 32 + c4]) = o;
}

// ---------------------------------------------------------------------------
__global__ __launch_bounds__(256) void f32_to_bf16(
    const float* __restrict__ in, ushort* __restrict__ out)
{
    const int i = (blockIdx.x * 256 + threadIdx.x) * 4;
    float4 v = *reinterpret_cast<const float4*>(&in[i]);
    short4 o = {f2bf(v.x), f2bf(v.y), f2bf(v.z), f2bf(v.w)};
    *reinterpret_cast<short4*>(&out[i]) = o;
}

// ---------------------------------------------------------------------------
// bf16 MFMA GEMM core v2: async global_load_lds staging, double-buffered,
// ONE barrier per BK=64 step.
// LDS tile: linear [64 rows][64 ushorts] per buffer (8 KB). Both-sides XOR
// swizzle: 16B col-slot s stored at s^(row&7); ds_read applies the same XOR.
// Bank-balanced: each ds_read_b128 spreads exactly 8 words/bank.
// ---------------------------------------------------------------------------
__device__ __forceinline__ void gemm_core64(
    const ushort* __restrict__ A, const ushort* __restrict__ Wt, int K,
    int row0, int col0, ushort* sA, ushort* sW, f32x4 acc[2][2])
{
    const int tid  = threadIdx.x;
    const int lane = tid & 63;
    const int wid  = tid >> 6;
    const int wr = wid >> 1, wc = wid & 1;
    const int g = lane >> 4, nn = lane & 15;

    // staging: thread t covers rows r0 (inst0) and r0+32 (inst1), 16B slot t&7
    const int r0 = tid >> 3;                       // 0..31
    const int sx = ((tid & 7) ^ (r0 & 7)) << 3;    // pre-swizzled ushort col

    const ushort* Ap = &A[(size_t)(row0 + r0) * K + sx];
    const ushort* Wp = &Wt[(size_t)(col0 + r0) * K + sx];
    const size_t rstep = (size_t)32 * K;

    ushort* ldsA = sA + wid * 512;     // wave-uniform dest base (+ lane*16B by HW)
    ushort* ldsW = sW + wid * 512;

    // prologue: stage k0=0 into buffer 0
    gload_lds16(Ap,         ldsA);
    gload_lds16(Ap + rstep, ldsA + 2048);
    gload_lds16(Wp,         ldsW);
    gload_lds16(Wp + rstep, ldsW + 2048);

    const int ra = (wr * 32 + nn) * 64, rb = ra + 16 * 64;
    const int rc = (wc * 32 + nn) * 64, rd = rc + 16 * 64;
    const int m7 = nn & 7;

    int cur = 0;
    __syncthreads();
    for (int k0 = 0; k0 < K; k0 += 64) {
        if (k0 + 64 < K) {          // issue next tile's DMA (in flight across MFMA)
            ushort* lA = ldsA + (cur ^ 1) * 4096;
            ushort* lW = ldsW + (cur ^ 1) * 4096;
            gload_lds16(Ap + k0 + 64,         lA);
            gload_lds16(Ap + k0 + 64 + rstep, lA + 2048);
            gload_lds16(Wp + k0 + 64,         lW);
            gload_lds16(Wp + k0 + 64 + rstep, lW + 2048);
        }
        const ushort* a = sA + cur * 4096;
        const ushort* w = sW + cur * 4096;
#pragma unroll
        for (int sk = 0; sk < 2; ++sk) {
            const int sw = ((sk * 4 + g) ^ m7) << 3;   // swizzled 16B slot
            bf16x8 a0 = *reinterpret_cast<const bf16x8*>(&a[ra + sw]);
            bf16x8 a1 = *reinterpret_cast<const bf16x8*>(&a[rb + sw]);
            bf16x8 w0 = *reinterpret_cast<const bf16x8*>(&w[rc + sw]);
            bf16x8 w1 = *reinterpret_cast<const bf16x8*>(&w[rd + sw]);
            acc[0][0] = __builtin_amdgcn_mfma_f32_16x16x32_bf16(a0, w0, acc[0][0], 0, 0, 0);
            acc[0][1] = __builtin_amdgcn_mfma_f32_16x16x32_bf16(a0, w1, acc[0][1], 0, 0, 0);
            acc[1][0] = __builtin_amdgcn_mfma_f32_16x16x32_bf16(a1, w0, acc[1][0], 0, 0, 0);
            acc[1][1] = __builtin_amdgcn_mfma_f32_16x16x32_bf16(a1, w1, acc[1][1], 0, 0, 0);
        }
        __syncthreads();            // drains vmcnt (next tile landed) + lgkm
        cur ^= 1;
    }
}

// ---------------------------------------------------------------------------
// Generic GEMM + epilogue. EPI: 0 none, 1 exact GELU, 2 +res (fp32).
// ---------------------------------------------------------------------------
template<int EPI, int OUTBF>
__global__ __launch_bounds__(256) void gemm_bf16(
    const ushort* __restrict__ A, const ushort* __restrict__ Wt,
    const float* __restrict__ bias, const float* __restrict__ res,
    void* __restrict__ Cout, int M, int N, int K)
{
    __shared__ __align__(16) ushort sA[2 * 4096];
    __shared__ __align__(16) ushort sW[2 * 4096];
    const int row0 = blockIdx.y * 64, col0 = blockIdx.x * 64;
    f32x4 acc[2][2] = {};
    gemm_core64(A, Wt, K, row0, col0, sA, sW, acc);

    const int lane = threadIdx.x & 63;
    const int wid  = threadIdx.x >> 6;
    const int wr = wid >> 1, wc = wid & 1;
    const int g = lane >> 4, nn = lane & 15;
#pragma unroll
    for (int mi = 0; mi < 2; ++mi)
#pragma unroll
    for (int ni = 0; ni < 2; ++ni)
#pragma unroll
    for (int r = 0; r < 4; ++r) {
        const int m = row0 + wr * 32 + mi * 16 + g * 4 + r;
        const int c = col0 + wc * 32 + ni * 16 + nn;
        float v = acc[mi][ni][r] + bias[c];
        if (EPI == 1) v = 0.5f * v * (1.0f + erff(v * 0.70710678118654752f));
        if (EPI == 2) v += res[(size_t)m * N + c];
        if (OUTBF) ((ushort*)Cout)[(size_t)m * N + c] = (ushort)f2bf(v);
        else       ((float*)Cout)[(size_t)m * N + c] = v;
    }
}

// ---------------------------------------------------------------------------
// Fused QKV GEMM (v2 core; epilogue unchanged).
// ---------------------------------------------------------------------------
__global__ __launch_bounds__(256) void gemm_qkv(
    const ushort* __restrict__ A,
    const ushort* __restrict__ WqT, const ushort* __restrict__ WkT,
    const ushort* __restrict__ WvT,
    const float* __restrict__ bq, const float* __restrict__ bk,
    const float* __restrict__ bv,
    ushort* __restrict__ Qb, ushort* __restrict__ Kb, ushort* __restrict__ Vt)
{
    __shared__ __align__(16) ushort sA[2 * 4096];
    __shared__ __align__(16) ushort sW[2 * 4096];
    const int nb = blockIdx.x;
    const int wsel = nb >> 2;
    const int col0 = (nb & 3) * 64;
    const int row0 = blockIdx.y * 64;
    const ushort* Wt = (wsel == 0) ? WqT : (wsel == 1) ? WkT : WvT;
    const float* bias = (wsel == 0) ? bq : (wsel == 1) ? bk : bv;

    f32x4 acc[2][2] = {};
    gemm_core64(A, Wt, 256, row0, col0, sA, sW, acc);

    const int lane = threadIdx.x & 63;
    const int wid  = threadIdx.x >> 6;
    const int wr = wid >> 1, wc = wid & 1;
    const int g = lane >> 4, nn = lane & 15;
    ushort* QK = (wsel == 0) ? Qb : Kb;
#pragma unroll
    for (int mi = 0; mi < 2; ++mi)
#pragma unroll
    for (int ni = 0; ni < 2; ++ni)
#pragma unroll
    for (int r = 0; r < 4; ++r) {
        const int m = row0 + wr * 32 + mi * 16 + g * 4 + r;
        const int c = col0 + wc * 32 + ni * 16 + nn;
        const float v = acc[mi][ni][r] + bias[c];
        if (wsel < 2) {
            QK[(size_t)m * D_ + c] = (ushort)f2bf(v);
        } else {
            const int b = m >> 11, l = m & 2047;
            const int h = c >> 5,  d = c & 31;
            Vt[(size_t)((b * 8 + h) * 32 + d) * L_ + l] = (ushort)f2bf(v);
        }
    }
}

// ---------------------------------------------------------------------------
// LayerNorm over D=256 -> bf16 out. One block per row.  (unchanged)
// ---------------------------------------------------------------------------
__global__ __launch_bounds__(256) void ln_kernel(
    const float* __restrict__ x, const float* __restrict__ g,
    const float* __restrict__ b, ushort* __restrict__ y)
{
    const int row = blockIdx.x;
    const int tid = threadIdx.x;
    const float v = x[row * D_ + tid];
    float s = v, s2 = v * v;
#pragma unroll
    for (int off = 32; off > 0; off >>= 1) {
        s  += __shfl_xor(s,  off);
        s2 += __shfl_xor(s2, off);
    }
    __shared__ float ls[4], ls2[4];
    const int wid = tid >> 6;
    if ((tid & 63) == 0) { ls[wid] = s; ls2[wid] = s2; }
    __syncthreads();
    s  = ls[0]  + ls[1]  + ls[2]  + ls[3];
    s2 = ls2[0] + ls2[1] + ls2[2] + ls2[3];
    const float m   = s * (1.0f / D_);
    const float var = s2 * (1.0f / D_) - m * m;
    const float r   = rsqrtf(var + 1e-5f);
    y[row * D_ + tid] = (ushort)f2bf((v - m) * r * g[tid] + b[tid]);
}

// ---------------------------------------------------------------------------
// MFMA evidence attention v6: LDS-staged K/V (as v5), plus:
//  - Q fragment pre-scaled by 1/sqrt(32): no per-score multiply
//  - esum via ones-MFMA: accS = mfma(ones, pa, accS). Constant-A MFMA makes
//    every C row equal to sum_k P[k][q], so each lane holds the FULL row sum
//    in accS[0] at the end -> no cross-lane reduce.
// ---------------------------------------------------------------------------
__global__ __launch_bounds__(256) void attn_mfma(
    const ushort* __restrict__ Qb, const ushort* __restrict__ Kb,
    const ushort* __restrict__ Vt, ushort* __restrict__ O,
    float* __restrict__ unc, const float* __restrict__ ev_scale,
    const float* __restrict__ ev_bias, int layer)
{
    const int bh = blockIdx.y;
    const int b  = bh >> 3;
    const int h  = bh & 7;
    const int tid  = threadIdx.x;
    const int wv   = tid >> 6;
    const int lane = tid & 63;
    const int g = lane >> 4;
    const int n = lane & 15;
    const int q  = blockIdx.x * 64 + wv * 16 + n;
    const float scale = ev_scale[layer];
    const float cb    = 1.0f + ev_bias[layer];
    const float isq   = 0.17677669529663687f;   // 1/sqrt(32)

    __shared__ __align__(16) ushort sK[2][64][40];
    __shared__ __align__(16) ushort sV[2][32][72];

    const size_t qk0 = (size_t)b * L_ * D_ + h * HD_;

    // Q fragment pre-scaled by isq
    bf16x8 qf;
    {
        const bf16x8 qr = *reinterpret_cast<const bf16x8*>(&Qb[qk0 + (size_t)q * D_ + g * 8]);
#pragma unroll
        for (int j = 0; j < 8; ++j) {
            const float qv = __builtin_bit_cast(float, ((unsigned)(unsigned short)qr[j]) << 16);
            qf[j] = f2bf(qv * isq);
        }
    }
    bf16x8 ones;
#pragma unroll
    for (int j = 0; j < 8; ++j) ones[j] = (short)0x3F80;   // bf16 1.0

    const int krow = tid >> 2, kch = (tid & 3) * 8;
    const int vrow = tid >> 3, vch = (tid & 7) * 8;
    const ushort* ksrc = Kb + qk0 + (size_t)krow * D_ + kch;
    const ushort* vsrc = Vt + (size_t)((b * 8 + h) * 32 + vrow) * L_ + vch;

    f32x4 acc0 = {0.f, 0.f, 0.f, 0.f};
    f32x4 acc1 = {0.f, 0.f, 0.f, 0.f};
    f32x4 accS = {0.f, 0.f, 0.f, 0.f};
    const f32x4 zero = {0.f, 0.f, 0.f, 0.f};

    bf16x8 kreg = *reinterpret_cast<const bf16x8*>(ksrc);
    bf16x8 vreg = *reinterpret_cast<const bf16x8*>(vsrc);

    int cur = 0;
    for (int t = 0; t < L_; t += 64) {
        *reinterpret_cast<bf16x8*>(&sK[cur][krow][kch]) = kreg;
        *reinterpret_cast<bf16x8*>(&sV[cur][vrow][vch]) = vreg;
        if (t + 64 < L_) {
            kreg = *reinterpret_cast<const bf16x8*>(ksrc + (size_t)(t + 64) * D_);
            vreg = *reinterpret_cast<const bf16x8*>(vsrc + (t + 64));
        }
        __syncthreads();

#pragma unroll
        for (int tt = 0; tt < 64; tt += 32) {
            bf16x8 kf0 = *reinterpret_cast<const bf16x8*>(&sK[cur][tt + n][g * 8]);
            bf16x8 kf1 = *reinterpret_cast<const bf16x8*>(&sK[cur][tt + 16 + n][g * 8]);

            f32x4 s0 = __builtin_amdgcn_mfma_f32_16x16x32_bf16(kf0, qf, zero, 0, 0, 0);
            f32x4 s1 = __builtin_amdgcn_mfma_f32_16x16x32_bf16(kf1, qf, zero, 0, 0, 0);

            short4 va = *reinterpret_cast<const short4*>(&sV[cur][n][tt + g * 4]);
            short4 vb = *reinterpret_cast<const short4*>(&sV[cur][n][tt + 16 + g * 4]);
            short4 vc = *reinterpret_cast<const short4*>(&sV[cur][n + 16][tt + g * 4]);
            short4 vd = *reinterpret_cast<const short4*>(&sV[cur][n + 16][tt + 16 + g * 4]);
            bf16x8 vf0 = {va.x, va.y, va.z, va.w, vb.x, vb.y, vb.z, vb.w};
            bf16x8 vf1 = {vc.x, vc.y, vc.z, vc.w, vd.x, vd.y, vd.z, vd.w};

            bf16x8 pa;
#pragma unroll
            for (int r = 0; r < 4; ++r) pa[r]     = f2bf(fmaf(__expf(s0[r]), scale, cb));
#pragma unroll
            for (int r = 0; r < 4; ++r) pa[r + 4] = f2bf(fmaf(__expf(s1[r]), scale, cb));

            acc0 = __builtin_amdgcn_mfma_f32_16x16x32_bf16(vf0, pa, acc0, 0, 0, 0);
            acc1 = __builtin_amdgcn_mfma_f32_16x16x32_bf16(vf1, pa, acc1, 0, 0, 0);
            accS = __builtin_amdgcn_mfma_f32_16x16x32_bf16(ones, pa, accS, 0, 0, 0);
        }
        cur ^= 1;
    }

    const float inv = 1.0f / accS[0];   // full row sum, every lane

    ushort* op = &O[qk0 + (size_t)q * D_ + g * 4];
    short4 o0 = {f2bf(acc0[0] * inv), f2bf(acc0[1] * inv), f2bf(acc0[2] * inv), f2bf(acc0[3] * inv)};
    short4 o1 = {f2bf(acc1[0] * inv), f2bf(acc1[1] * inv), f2bf(acc1[2] * inv), f2bf(acc1[3] * inv)};
    *reinterpret_cast<short4*>(op)      = o0;
    *reinterpret_cast<short4*>(op + 16) = o1;

    if (g == 0) {
        const float u = (float)L_ * inv;
        const int uidx = bh * L_ + q;
        unc[uidx] = (layer == 0) ? u : (unc[uidx] + u);
    }
}

// ---------------------------------------------------------------------------
__global__ __launch_bounds__(256) void unc_final(
    const float* __restrict__ unc, float* __restrict__ out_unc,
    float* __restrict__ out_abst)
{
    const int i = blockIdx.x * 256 + threadIdx.x;
    const float u = unc[i] * 0.25f;
    out_unc[i]  = u;
    out_abst[i] = (u > 0.3f) ? 1.0f : 0.0f;
}

// ---------------------------------------------------------------------------
extern "C" void kernel_launch(void* const* d_in, const int* in_sizes, int n_in,
                              void* d_out, int out_size, void* d_ws, size_t ws_size,
                              hipStream_t stream)
{
    const float* x    = (const float*)d_in[0];
    const float* Win  = (const float*)d_in[1];
    const float* bin_ = (const float*)d_in[2];
    const float* Wq   = (const float*)d_in[3];
    const float* bq   = (const float*)d_in[4];
    const float* Wk   = (const float*)d_in[5];
    const float* bk   = (const float*)d_in[6];
    const float* Wv   = (const float*)d_in[7];
    const float* bv   = (const float*)d_in[8];
    const float* Wo   = (const float*)d_in[9];
    const float* bo   = (const float*)d_in[10];
    const float* evs  = (const float*)d_in[11];
    const float* evb  = (const float*)d_in[12];
    const float* W1   = (const float*)d_in[13];
    const float* b1   = (const float*)d_in[14];
    const float* W2   = (const float*)d_in[15];
    const float* b2   = (const float*)d_in[16];
    const float* n1g  = (const float*)d_in[17];
    const float* n1b  = (const float*)d_in[18];
    const float* n2g  = (const float*)d_in[19];
    const float* n2b  = (const float*)d_in[20];
    const float* fng  = (const float*)d_in[21];
    const float* fnb  = (const float*)d_in[22];
    const float* Wout = (const float*)d_in[23];
    const float* bout = (const float*)d_in[24];

    char* ws = (char*)d_ws;
    float*  h    = (float*) (ws);                  // 4 MB fp32 residual stream
    ushort* tmpb = (ushort*)(ws + (4  << 20));     // 2 MB bf16 (LN out / x-bf16)
    ushort* Qb   = (ushort*)(ws + (6  << 20));     // 2 MB
    ushort* Kb   = (ushort*)(ws + (8  << 20));     // 2 MB
    ushort* Vt   = (ushort*)(ws + (10 << 20));     // 2 MB (transposed V)
    ushort* Ob   = (ushort*)(ws + (12 << 20));     // 2 MB (attn out)
    ushort* ffb  = (ushort*)(ws + (6  << 20));     // 8 MB, overlays Qb..Ob (dead by FF1)
    float*  unc  = (float*) (ws + (14 << 20));     // 128 KB
    ushort* T    = (ushort*)(ws + (15 << 20));     // 6.55 MB transposed bf16 weights

    ushort* winT  = T;
    ushort* woutT = T + 65536 * 17 + 2097152;

    float* out_main = (float*)d_out;
    float* out_unc  = out_main + M_ * D_;
    float* out_abst = out_unc + B_ * H_ * L_;

    const dim3 blk(256);
    const dim3 g256(4, 64);     // N=256 GEMMs
    const dim3 g1024(16, 64);   // N=1024 GEMM
    const dim3 gqkv(12, 64);
    const dim3 gattn(L_ / 64, B_ * H_);

    transpose_weights<<<3200, blk, 0, stream>>>(Win, Wq, Wk, Wv, Wo, W1, W2, Wout, T);
    f32_to_bf16<<<1024, blk, 0, stream>>>(x, tmpb);
    gemm_bf16<0, 0><<<g256, blk, 0, stream>>>(tmpb, winT, bin_, nullptr, h, M_, D_, D_);

    for (int i = 0; i < LY_; ++i) {
        ushort* wqT = T + 65536 * (1 + i);
        ushort* wkT = T + 65536 * (5 + i);
        ushort* wvT = T + 65536 * (9 + i);
        ushort* woT = T + 65536 * (13 + i);
        ushort* w1T = T + 65536 * 17 + i * 262144;
        ushort* w2T = T + 65536 * 17 + 1048576 + i * 262144;

        ln_kernel<<<M_, blk, 0, stream>>>(h, n1g + i * D_, n1b + i * D_, tmpb);
        gemm_qkv<<<gqkv, blk, 0, stream>>>(tmpb, wqT, wkT, wvT,
                                           bq + i * D_, bk + i * D_, bv + i * D_,
                                           Qb, Kb, Vt);
        attn_mfma<<<gattn, blk, 0, stream>>>(Qb, Kb, Vt, Ob, unc, evs, evb, i);
        gemm_bf16<2, 0><<<g256, blk, 0, stream>>>(Ob, woT, bo + i * D_, h, h, M_, D_, D_);
        ln_kernel<<<M_, blk, 0, stream>>>(h, n2g + i * D_, n2b + i * D_, tmpb);
        gemm_bf16<1, 1><<<g1024, blk, 0, stream>>>(tmpb, w1T, b1 + i * F_, nullptr, ffb, M_, F_, D_);
        gemm_bf16<2, 0><<<g256, blk, 0, stream>>>(ffb, w2T, b2 + i * D_, h, h, M_, D_, F_);
    }

    ln_kernel<<<M_, blk, 0, stream>>>(h, fng, fnb, tmpb);
    gemm_bf16<0, 0><<<g256, blk, 0, stream>>>(tmpb, woutT, bout, nullptr, out_main, M_, D_, D_);
    unc_final<<<(B_ * H_ * L_) / 256, blk, 0, stream>>>(unc, out_unc, out_abst);
}